// Round 1
// baseline (1224.282 us; speedup 1.0000x reference)
//
#include <hip/hip_runtime.h>
#include <hip/hip_bf16.h>
#include <cstdint>
#include <cstddef>

typedef __bf16 bf16;
typedef __bf16 bf16x2 __attribute__((ext_vector_type(2)));
typedef __bf16 bf16x4 __attribute__((ext_vector_type(4)));
typedef __bf16 bf16x8 __attribute__((ext_vector_type(8)));
typedef float f32x4 __attribute__((ext_vector_type(4)));

// ---------------- constants ----------------
#define EDIM 2048
#define SEQ  2048
#define BATCH 2
#define NH   32
#define NKV  8
#define HD   64
#define FF   8192
#define NTOK 4096          // BATCH*SEQ
#define QKVN 3072          // EDIM + 2*512

// async 16B global -> LDS (lane-contiguous LDS layout required)
__device__ __forceinline__ void gld_lds16(const void* gp, void* lp) {
    __builtin_amdgcn_global_load_lds(
        (__attribute__((address_space(1))) void*)(gp),
        (__attribute__((address_space(3))) void*)(lp), 16, 0, 0);
}

// ---------------- fp32 -> bf16 convert ----------------
__global__ __launch_bounds__(256)
void cvt_f32_bf16(const float* __restrict__ in, bf16* __restrict__ out, long n4) {
    long i = (long)blockIdx.x * blockDim.x + threadIdx.x;
    long stride = (long)gridDim.x * blockDim.x;
    for (; i < n4; i += stride) {
        float4 v = ((const float4*)in)[i];
        bf16x4 o;
        o[0] = (bf16)v.x; o[1] = (bf16)v.y; o[2] = (bf16)v.z; o[3] = (bf16)v.w;
        ((bf16x4*)out)[i] = o;
    }
}

// ---------------- RMSNorm: fp32 row -> bf16 row ----------------
__global__ __launch_bounds__(256)
void rmsnorm_bf16(const float* __restrict__ x, const float* __restrict__ w,
                  bf16* __restrict__ out) {
    __shared__ float red[4];
    const int row = blockIdx.x;
    const long base = (long)row * EDIM;
    const int t = threadIdx.x;
    float4 v0 = *(const float4*)(x + base + t * 4);
    float4 v1 = *(const float4*)(x + base + 1024 + t * 4);
    float ss = v0.x*v0.x + v0.y*v0.y + v0.z*v0.z + v0.w*v0.w
             + v1.x*v1.x + v1.y*v1.y + v1.z*v1.z + v1.w*v1.w;
    #pragma unroll
    for (int off = 1; off < 64; off <<= 1) ss += __shfl_xor(ss, off, 64);
    if ((t & 63) == 0) red[t >> 6] = ss;
    __syncthreads();
    float tot = red[0] + red[1] + red[2] + red[3];
    float inv = rsqrtf(tot * (1.0f / EDIM) + 1e-5f);
    float4 w0 = *(const float4*)(w + t * 4);
    float4 w1 = *(const float4*)(w + 1024 + t * 4);
    bf16x4 o0, o1;
    o0[0] = (bf16)(v0.x * inv * w0.x); o0[1] = (bf16)(v0.y * inv * w0.y);
    o0[2] = (bf16)(v0.z * inv * w0.z); o0[3] = (bf16)(v0.w * inv * w0.w);
    o1[0] = (bf16)(v1.x * inv * w1.x); o1[1] = (bf16)(v1.y * inv * w1.y);
    o1[2] = (bf16)(v1.z * inv * w1.z); o1[3] = (bf16)(v1.w * inv * w1.w);
    *(bf16x4*)(out + base + t * 4) = o0;
    *(bf16x4*)(out + base + 1024 + t * 4) = o1;
}

// ---------------- NT GEMM (128x128, m97 structure) for N=2048 cases ----------------
// EPI: 0 = f32 store, 1 = bf16 store, 2 = f32 store + f32 residual add,
//      3 = bf16 in-place: Cv[idx] = silu(Cv[idx]) * acc   (SwiGLU fuse)
template<int EPI>
__global__ __launch_bounds__(256, 2)
void gemm_nt(const bf16* __restrict__ A, const bf16* __restrict__ B,
             void* __restrict__ Cv, const float* __restrict__ res,
             int M, int N, int K) {
    __shared__ bf16 As[128 * 32];
    __shared__ bf16 Bs[128 * 32];
    const int tid = threadIdx.x;
    const int lane = tid & 63;
    const int wave = tid >> 6;
    const int wm = (wave >> 1) * 64;
    const int wn = (wave & 1) * 64;
    const int bm = blockIdx.y * 128;
    const int bn = blockIdx.x * 128;
    const int lrow = lane & 15;
    const int koff = (lane >> 4) * 8;

    f32x4 acc[4][4] = {};

    for (int k0 = 0; k0 < K; k0 += 32) {
        __syncthreads();
        #pragma unroll
        for (int t = 0; t < 2; ++t) {
            int c = tid + t * 256;           // 512 chunks of 16B per tile
            int r = c >> 2;
            int kc = (c & 3) * 8;
            gld_lds16(A + (long)(bm + r) * K + k0 + kc, As + c * 8);
            gld_lds16(B + (long)(bn + r) * K + k0 + kc, Bs + c * 8);
        }
        __syncthreads();
        bf16x8 af[4], bfr[4];
        #pragma unroll
        for (int t = 0; t < 4; ++t) {
            af[t]  = *(const bf16x8*)(As + (wm + t * 16 + lrow) * 32 + koff);
            bfr[t] = *(const bf16x8*)(Bs + (wn + t * 16 + lrow) * 32 + koff);
        }
        #pragma unroll
        for (int i = 0; i < 4; ++i)
            #pragma unroll
            for (int j = 0; j < 4; ++j)
                acc[i][j] = __builtin_amdgcn_mfma_f32_16x16x32_bf16(af[i], bfr[j], acc[i][j], 0, 0, 0);
    }

    const int row0 = bm + wm + (lane >> 4) * 4;
    const int col0 = bn + wn + (lane & 15);
    #pragma unroll
    for (int i = 0; i < 4; ++i) {
        #pragma unroll
        for (int j = 0; j < 4; ++j) {
            int col = col0 + j * 16;
            #pragma unroll
            for (int r = 0; r < 4; ++r) {
                long idx = (long)(row0 + i * 16 + r) * N + col;
                float v = acc[i][j][r];
                if (EPI == 0) {
                    ((float*)Cv)[idx] = v;
                } else if (EPI == 1) {
                    ((bf16*)Cv)[idx] = (bf16)v;
                } else if (EPI == 2) {
                    ((float*)Cv)[idx] = v + res[idx];
                } else {                       // EPI == 3: SwiGLU in-place
                    float u = (float)((bf16*)Cv)[idx];
                    float sl = u / (1.0f + __expf(-u));
                    ((bf16*)Cv)[idx] = (bf16)(sl * v);
                }
            }
        }
    }
}

// ---------------- NT GEMM (256x256, counted-vmcnt pipelined) ----------------
// 512 threads = 8 waves (2M x 4N), per-wave C = 128x64 (acc[8][4] of 16x16).
// LDS 128 KiB dynamic: 2 buffers x {A_ks0,A_ks1,B_ks0,B_ks1} chunks of 256x32 bf16.
// Per K-tile (BK=64): 2 phases (one per 32-wide k-chunk). Each phase:
//   12x ds_read_b128 -> issue 4 global_load_lds (same-ks chunks of NEXT tile)
//   -> s_waitcnt vmcnt(4) (lands the chunk-pair the NEXT phase reads; newest
//      4 loads stay in flight -- never drains to 0 in the main loop)
//   -> s_barrier -> lgkmcnt(0) -> setprio(1) + 32 MFMA + setprio(0) -> s_barrier.
// Race-freedom: every chunk's loads are covered by a vmcnt+barrier that is
// >=1 full barrier before any wave's ds_read of that chunk; stage writes go to
// the opposite buffer, whose readers passed 2 barriers earlier. sched_barrier(0)
// after each s_barrier pins ds_reads from hoisting across the cross-wave fence.
// LDS row stride = 32 bf16 = 64B -> <=2-way bank aliasing on ds_read_b128 (free).
#define G256_CH 8192            // elems per chunk (256*32)
#define G256_BUF 32768          // elems per buffer (4 chunks)

template<int KS, bool DO_STAGE, int VN>
__device__ __forceinline__ void g256_phase(
    bf16* __restrict__ smem, int bufsel, long koff,
    const bf16* __restrict__ pa, const bf16* __restrict__ pb, long rstep,
    int tid, int aoff, int boff, f32x4 (&acc)[8][4]) {
    const bf16* ca = smem + bufsel * G256_BUF + KS * G256_CH;          // A chunk
    bf16x8 af[8], bfr[4];
    #pragma unroll
    for (int i = 0; i < 8; ++i) af[i] = *(const bf16x8*)(ca + aoff + i * 512);
    #pragma unroll
    for (int j = 0; j < 4; ++j) bfr[j] = *(const bf16x8*)(ca + 2 * G256_CH + boff + j * 512);
    if (DO_STAGE) {
        bf16* d = smem + (bufsel ^ 1) * G256_BUF + KS * G256_CH + tid * 8;
        gld_lds16(pa + koff + KS * 32,         d);
        gld_lds16(pa + koff + KS * 32 + rstep, d + 4096);
        gld_lds16(pb + koff + KS * 32,         d + 2 * G256_CH);
        gld_lds16(pb + koff + KS * 32 + rstep, d + 2 * G256_CH + 4096);
    }
    asm volatile("s_waitcnt vmcnt(%0)" :: "n"(VN) : "memory");
    __builtin_amdgcn_s_barrier();
    __builtin_amdgcn_sched_barrier(0);
    asm volatile("s_waitcnt lgkmcnt(0)" ::: "memory");
    __builtin_amdgcn_sched_barrier(0);
    __builtin_amdgcn_s_setprio(1);
    #pragma unroll
    for (int i = 0; i < 8; ++i)
        #pragma unroll
        for (int j = 0; j < 4; ++j)
            acc[i][j] = __builtin_amdgcn_mfma_f32_16x16x32_bf16(af[i], bfr[j], acc[i][j], 0, 0, 0);
    __builtin_amdgcn_s_setprio(0);
    __builtin_amdgcn_s_barrier();
    __builtin_amdgcn_sched_barrier(0);
}

template<int EPI>
__global__ __launch_bounds__(512, 2)
void gemm256_nt(const bf16* __restrict__ A, const bf16* __restrict__ B,
                void* __restrict__ Cv, const float* __restrict__ res,
                int M, int N, int K) {
    extern __shared__ bf16 smem[];                 // 2 * 32768 elems = 128 KiB
    const int tid = threadIdx.x;
    const int lane = tid & 63, wave = tid >> 6;
    const int wr = wave >> 2, wc = wave & 3;
    const int lrow = lane & 15, g = lane >> 4;
    const int bm = blockIdx.y * 256, bn = blockIdx.x * 256;
    const long Kl = (long)K;
    const bf16* pa = A + (long)(bm + (tid >> 2)) * Kl + (tid & 3) * 8;
    const bf16* pb = B + (long)(bn + (tid >> 2)) * Kl + (tid & 3) * 8;
    const long rstep = 128 * Kl;
    const int aoff = (wr * 128 + lrow) * 32 + g * 8;
    const int boff = (wc * 64 + lrow) * 32 + g * 8;

    f32x4 acc[8][4] = {};

    // prologue: stage tile 0 fully (8 loads); land ks0, keep ks1 in flight
    {
        bf16* d0 = smem + tid * 8;
        gld_lds16(pa,                 d0);
        gld_lds16(pa + rstep,         d0 + 4096);
        gld_lds16(pb,                 d0 + 2 * G256_CH);
        gld_lds16(pb + rstep,         d0 + 2 * G256_CH + 4096);
        bf16* d1 = d0 + G256_CH;
        gld_lds16(pa + 32,            d1);
        gld_lds16(pa + 32 + rstep,    d1 + 4096);
        gld_lds16(pb + 32,            d1 + 2 * G256_CH);
        gld_lds16(pb + 32 + rstep,    d1 + 2 * G256_CH + 4096);
    }
    asm volatile("s_waitcnt vmcnt(4)" ::: "memory");
    __builtin_amdgcn_s_barrier();
    __builtin_amdgcn_sched_barrier(0);

    const int NT = K >> 6;
    int bufsel = 0;
    for (int t = 0; t < NT - 1; ++t) {
        long koff = (long)(t + 1) * 64;
        g256_phase<0, true, 4>(smem, bufsel, koff, pa, pb, rstep, tid, aoff, boff, acc);
        g256_phase<1, true, 4>(smem, bufsel, koff, pa, pb, rstep, tid, aoff, boff, acc);
        bufsel ^= 1;
    }
    // final tile: no staging; drain the last in-flight chunk-pair before ks1 reads
    g256_phase<0, false, 0>(smem, bufsel, 0, pa, pb, rstep, tid, aoff, boff, acc);
    g256_phase<1, false, 0>(smem, bufsel, 0, pa, pb, rstep, tid, aoff, boff, acc);

    const int row0 = bm + wr * 128 + g * 4;
    const int col0 = bn + wc * 64 + lrow;
    #pragma unroll
    for (int i = 0; i < 8; ++i) {
        #pragma unroll
        for (int j = 0; j < 4; ++j) {
            int col = col0 + j * 16;
            #pragma unroll
            for (int r = 0; r < 4; ++r) {
                long idx = (long)(row0 + i * 16 + r) * N + col;
                float v = acc[i][j][r];
                if (EPI == 0) {
                    ((float*)Cv)[idx] = v;
                } else if (EPI == 1) {
                    ((bf16*)Cv)[idx] = (bf16)v;
                } else if (EPI == 2) {
                    ((float*)Cv)[idx] = v + res[idx];
                } else {                       // EPI == 3: SwiGLU in-place
                    float u = (float)((bf16*)Cv)[idx];
                    float sl = u / (1.0f + __expf(-u));
                    ((bf16*)Cv)[idx] = (bf16)(sl * v);
                }
            }
        }
    }
}

// ---------------- RoPE prep: qkv bf16 [4096,3072] -> Q [B,H,S,64], K [B,KH,S,64] ----------------
__global__ __launch_bounds__(256)
void rope_prep(const bf16* __restrict__ qkv, const float* __restrict__ fr,
               bf16* __restrict__ Qo, bf16* __restrict__ Ko) {
    const int row = blockIdx.x;            // b*SEQ + s
    const int b = row >> 11, s = row & 2047;
    const int t = threadIdx.x;
    const long rbase = (long)row * QKVN;
    #pragma unroll
    for (int i = 0; i < 4; ++i) {          // 1024 q pairs
        int p = t + i * 256;
        int hh = p >> 5, d = p & 31;
        bf16x2 xv = *(const bf16x2*)(qkv + rbase + hh * 64 + 2 * d);
        float x0 = (float)xv[0], x1 = (float)xv[1];
        float2 cs = *(const float2*)(fr + (long)(s * 32 + d) * 2);
        bf16x2 o;
        o[0] = (bf16)(x0 * cs.x - x1 * cs.y);
        o[1] = (bf16)(x1 * cs.x + x0 * cs.y);
        *(bf16x2*)(Qo + ((long)(b * NH + hh) * SEQ + s) * HD + 2 * d) = o;
    }
    {                                       // 256 k pairs
        int kh = t >> 5, d = t & 31;
        bf16x2 xv = *(const bf16x2*)(qkv + rbase + EDIM + kh * 64 + 2 * d);
        float x0 = (float)xv[0], x1 = (float)xv[1];
        float2 cs = *(const float2*)(fr + (long)(s * 32 + d) * 2);
        bf16x2 o;
        o[0] = (bf16)(x0 * cs.x - x1 * cs.y);
        o[1] = (bf16)(x1 * cs.x + x0 * cs.y);
        *(bf16x2*)(Ko + ((long)(b * NKV + kh) * SEQ + s) * HD + 2 * d) = o;
    }
}

// ---------------- V prep: transpose into [B,KH,S/64,hd=64,kk=64] bf16 tiles ----------------
__global__ __launch_bounds__(256)
void v_prep(const bf16* __restrict__ qkv, bf16* __restrict__ Vt) {
    __shared__ bf16 tile[64 * 72];          // +8 pad to break transpose conflicts
    const int blk = blockIdx.x;             // b*256 + kvh*32 + st
    const int b = blk >> 8;
    const int kvh = (blk >> 5) & 7;
    const int st = blk & 31;
    const int t = threadIdx.x;
    #pragma unroll
    for (int i = 0; i < 2; ++i) {
        int c = t + i * 256;                // 512 chunks
        int kk = c >> 3, hdo = (c & 7) * 8;
        bf16x8 v = *(const bf16x8*)(qkv + (long)(b * SEQ + st * 64 + kk) * QKVN + 2560 + kvh * 64 + hdo);
        *(bf16x8*)(tile + kk * 72 + hdo) = v;
    }
    __syncthreads();
    const long obase = ((long)(b * NKV + kvh) * 32 + st) * 4096;
    #pragma unroll
    for (int i = 0; i < 2; ++i) {
        int c = t + i * 256;
        int hd = c >> 3, ko = (c & 7) * 8;
        bf16x8 v;
        #pragma unroll
        for (int j = 0; j < 8; ++j) v[j] = tile[(ko + j) * 72 + hd];
        *(bf16x8*)(Vt + obase + hd * 64 + ko) = v;
    }
}

// ---------------- flash attention (causal, GQA 4:1), barrier-free ----------------
// block = 128 q-rows x (b,h); 4 waves, each wave owns 32 q-rows independently.
__global__ __launch_bounds__(256)
void attn_fwd(const bf16* __restrict__ Q, const bf16* __restrict__ K,
              const bf16* __restrict__ Vt, bf16* __restrict__ Out) {
    __shared__ bf16 Ps[4 * 32 * 64];
    const int tid = threadIdx.x, lane = tid & 63, w = tid >> 6;
    const int qt = blockIdx.x;               // 128-row q tile
    const int bh = blockIdx.y;
    const int b = bh >> 5, h = bh & 31;
    const int kvh = h >> 2;
    const int g = lane >> 4, lrow = lane & 15;
    const int qrow = g * 4;
    const long qbase  = ((long)(b * NH + h) * SEQ + qt * 128 + w * 32) * HD;
    const long kvbase = ((long)(b * NKV + kvh) * SEQ) * HD;
    bf16* Pw = Ps + w * (32 * 64);

    bf16x8 qa[2][2];
    #pragma unroll
    for (int m = 0; m < 2; ++m)
        #pragma unroll
        for (int hf = 0; hf < 2; ++hf)
            qa[m][hf] = *(const bf16x8*)(Q + qbase + (long)(m * 16 + lrow) * HD + hf * 32 + g * 8);

    f32x4 acc[2][4] = {};
    float mi[2][4], li[2][4];
    #pragma unroll
    for (int m = 0; m < 2; ++m)
        #pragma unroll
        for (int r = 0; r < 4; ++r) { mi[m][r] = -1e30f; li[m][r] = 0.f; }

    const int ntiles = qt * 2 + (w >> 1) + 1;   // per-wave causal trip count

    for (int kt = 0; kt < ntiles; ++kt) {
        const bf16* Kt  = K  + kvbase + (long)kt * (64 * HD);
        const bf16* Vtt = Vt + kvbase + (long)kt * (64 * HD);

        f32x4 s[2][4];
        #pragma unroll
        for (int nt = 0; nt < 4; ++nt) {
            bf16x8 kb0 = *(const bf16x8*)(Kt + (nt * 16 + lrow) * HD + g * 8);
            bf16x8 kb1 = *(const bf16x8*)(Kt + (nt * 16 + lrow) * HD + 32 + g * 8);
            #pragma unroll
            for (int m = 0; m < 2; ++m) {
                f32x4 z = {};
                z = __builtin_amdgcn_mfma_f32_16x16x32_bf16(qa[m][0], kb0, z, 0, 0, 0);
                z = __builtin_amdgcn_mfma_f32_16x16x32_bf16(qa[m][1], kb1, z, 0, 0, 0);
                s[m][nt] = z * 0.125f;
            }
        }
        if (kt == ntiles - 1) {
            #pragma unroll
            for (int nt = 0; nt < 4; ++nt) {
                int kk = kt * 64 + nt * 16 + lrow;
                #pragma unroll
                for (int m = 0; m < 2; ++m) {
                    int q0 = qt * 128 + w * 32 + m * 16 + qrow;
                    #pragma unroll
                    for (int r = 0; r < 4; ++r)
                        if (kk > q0 + r) s[m][nt][r] = -1e30f;
                }
            }
        }
        #pragma unroll
        for (int m = 0; m < 2; ++m) {
            #pragma unroll
            for (int r = 0; r < 4; ++r) {
                float mx = fmaxf(fmaxf(s[m][0][r], s[m][1][r]), fmaxf(s[m][2][r], s[m][3][r]));
                #pragma unroll
                for (int off = 1; off < 16; off <<= 1)
                    mx = fmaxf(mx, __shfl_xor(mx, off, 64));
                float mnew = fmaxf(mi[m][r], mx);
                float alpha = __expf(mi[m][r] - mnew);
                mi[m][r] = mnew;
                float rs = 0.f;
                #pragma unroll
                for (int nt = 0; nt < 4; ++nt) {
                    float p = __expf(s[m][nt][r] - mnew);
                    s[m][nt][r] = p;
                    rs += p;
                }
                #pragma unroll
                for (int off = 1; off < 16; off <<= 1)
                    rs += __shfl_xor(rs, off, 64);
                li[m][r] = li[m][r] * alpha + rs;
                #pragma unroll
                for (int nt = 0; nt < 4; ++nt) acc[m][nt][r] *= alpha;
            }
        }
        // P: C-layout regs -> XOR-8 swizzled per-wave LDS -> A-layout frags.
        #pragma unroll
        for (int m = 0; m < 2; ++m)
            #pragma unroll
            for (int nt = 0; nt < 4; ++nt) {
                int cb = nt * 2 + (lrow >> 3);
                #pragma unroll
                for (int r = 0; r < 4; ++r) {
                    int row = m * 16 + qrow + r;
                    Pw[row * 64 + ((cb ^ (row & 7)) << 3) + (lrow & 7)] = (bf16)s[m][nt][r];
                }
            }
        bf16x8 pa[2][2];
        #pragma unroll
        for (int m = 0; m < 2; ++m)
            #pragma unroll
            for (int hf = 0; hf < 2; ++hf) {
                int row = m * 16 + lrow;
                int cbs = (hf * 4 + g) ^ (row & 7);
                pa[m][hf] = *(const bf16x8*)(Pw + row * 64 + cbs * 8);
            }
        #pragma unroll
        for (int nt = 0; nt < 4; ++nt) {
            bf16x8 vb0 = *(const bf16x8*)(Vtt + (nt * 16 + lrow) * HD + g * 8);
            bf16x8 vb1 = *(const bf16x8*)(Vtt + (nt * 16 + lrow) * HD + 32 + g * 8);
            #pragma unroll
            for (int m = 0; m < 2; ++m) {
                acc[m][nt] = __builtin_amdgcn_mfma_f32_16x16x32_bf16(pa[m][0], vb0, acc[m][nt], 0, 0, 0);
                acc[m][nt] = __builtin_amdgcn_mfma_f32_16x16x32_bf16(pa[m][1], vb1, acc[m][nt], 0, 0, 0);
            }
        }
    }

    const long obase = ((long)b * SEQ + qt * 128 + w * 32) * EDIM + h * 64;
    #pragma unroll
    for (int m = 0; m < 2; ++m)
        #pragma unroll
        for (int nt = 0; nt < 4; ++nt)
            #pragma unroll
            for (int r = 0; r < 4; ++r) {
                float v = acc[m][nt][r] / li[m][r];
                Out[obase + (long)(m * 16 + qrow + r) * EDIM + nt * 16 + lrow] = (bf16)v;
            }
}

// ---------------- launcher ----------------
extern "C" void kernel_launch(void* const* d_in, const int* in_sizes, int n_in,
                              void* d_out, int out_size, void* d_ws, size_t ws_size,
                              hipStream_t stream) {
    const float* x    = (const float*)d_in[0];
    // d_in[1] = attention_mask (always causal tril; handled analytically)
    const float* fr   = (const float*)d_in[2];
    const float* wqkv = (const float*)d_in[3];
    const float* wo   = (const float*)d_in[4];
    const float* w1   = (const float*)d_in[5];
    const float* w2   = (const float*)d_in[6];
    const float* w3   = (const float*)d_in[7];
    const float* anw  = (const float*)d_in[8];
    const float* fnw  = (const float*)d_in[9];
    float* out = (float*)d_out;

    // allow 128 KiB dynamic LDS for the 256^2 GEMM (idempotent; not a stream op)
    static int attr_done = 0;
    if (!attr_done) {
        hipFuncSetAttribute(reinterpret_cast<const void*>(gemm256_nt<1>),
                            hipFuncAttributeMaxDynamicSharedMemorySize, 131072);
        hipFuncSetAttribute(reinterpret_cast<const void*>(gemm256_nt<3>),
                            hipFuncAttributeMaxDynamicSharedMemorySize, 131072);
        attr_done = 1;
    }

    // ---- workspace budget (aliased layout), ~252 MiB ----
    const size_t SZ_WQKV = (size_t)QKVN * EDIM;     // 6291456
    const size_t SZ_WO   = (size_t)EDIM * EDIM;     // 4194304
    const size_t SZ_WFF  = (size_t)FF * EDIM;       // 16777216
    const size_t B_WQKV  = SZ_WQKV * 2;             // 12.6 MB
    const size_t B_WO    = SZ_WO * 2;               //  8.4 MB
    const size_t B_WFF   = SZ_WFF * 2;              // 33.6 MB
    const size_t B_HATTN = (size_t)NTOK * EDIM * 2; // 16.8 MB
    const size_t B_QKV   = (size_t)NTOK * QKVN * 2; // 25.2 MB
    const size_t B_SCR   = (size_t)NTOK * EDIM * 4; // 33.6 MB (h2 fp32; aliases Q/K/Vt)
    const size_t B_FF1   = (size_t)NTOK * FF * 2;   // 67.1 MB
    const size_t NEED = B_WQKV + B_WO + 3 * B_WFF + B_HATTN + B_QKV + B_SCR + B_FF1;
    if (ws_size < NEED) return;   // diagnostic: clean absmax-fail instead of GPU fault

    char* ws = (char*)d_ws;
    size_t off = 0;
    auto alloc = [&](size_t bytes) -> void* {
        void* p = ws + off;
        off += (bytes + 255) & ~(size_t)255;
        return p;
    };
    bf16* wqkv_b = (bf16*)alloc(B_WQKV);
    bf16* wo_b   = (bf16*)alloc(B_WO);
    bf16* w1_b   = (bf16*)alloc(B_WFF);
    bf16* w3_b   = (bf16*)alloc(B_WFF);
    bf16* w2_b   = (bf16*)alloc(B_WFF);
    bf16* h_attn = (bf16*)alloc(B_HATTN);           // h, then attn_out
    bf16* qkv_g  = (bf16*)alloc(B_QKV);             // qkv, then g
    char* scr    = (char*)alloc(B_SCR);             // Q/K/Vt region, then h2
    bf16* Qb  = (bf16*)scr;                                         // 16.8 MB
    bf16* Kb  = (bf16*)(scr + (size_t)BATCH * NH * SEQ * HD * 2);   //  4.2 MB
    bf16* Vtb = (bf16*)(scr + (size_t)BATCH * (NH + NKV) * SEQ * HD * 2); // 4.2 MB
    float* h2 = (float*)scr;                        // aliases Q/K/Vt (dead by then)
    bf16* ff1 = (bf16*)alloc(B_FF1);                // u, then act (in-place SwiGLU)
    bf16* g_b = qkv_g;                              // reuse (qkv dead after preps)

    // 1. weights -> bf16
    cvt_f32_bf16<<<512, 256, 0, stream>>>(wqkv, wqkv_b, (long)(SZ_WQKV / 4));
    cvt_f32_bf16<<<512, 256, 0, stream>>>(wo,   wo_b,   (long)(SZ_WO / 4));
    cvt_f32_bf16<<<512, 256, 0, stream>>>(w1,   w1_b,   (long)(SZ_WFF / 4));
    cvt_f32_bf16<<<512, 256, 0, stream>>>(w3,   w3_b,   (long)(SZ_WFF / 4));
    cvt_f32_bf16<<<512, 256, 0, stream>>>(w2,   w2_b,   (long)(SZ_WFF / 4));
    // 2. h = rmsnorm(x) * attn_norm_w  (bf16)
    rmsnorm_bf16<<<NTOK, 256, 0, stream>>>(x, anw, h_attn);
    // 3. qkv = h @ w_qkv^T  (bf16 out) -- 256^2 pipelined, 192 blocks
    gemm256_nt<1><<<dim3(QKVN / 256, NTOK / 256), 512, 131072, stream>>>(
        h_attn, wqkv_b, qkv_g, nullptr, NTOK, QKVN, EDIM);
    // 4. RoPE + layout prep
    rope_prep<<<NTOK, 256, 0, stream>>>(qkv_g, fr, Qb, Kb);
    v_prep<<<BATCH * NKV * (SEQ / 64), 256, 0, stream>>>(qkv_g, Vtb);
    // 5. attention -> attn_out (bf16, [4096,2048]); 128 q-rows per block
    attn_fwd<<<dim3(SEQ / 128, BATCH * NH), 256, 0, stream>>>(Qb, Kb, Vtb, h_attn);
    // 6. h2 = x + attn_out @ w_o^T  (fp32; h2 aliases dead Q/K/Vt)
    //    N=2048 -> only 128 blocks at 256^2 (half the CUs idle), keep 128^2 tile
    gemm_nt<2><<<dim3(EDIM / 128, NTOK / 128), 256, 0, stream>>>(
        h_attn, wo_b, h2, x, NTOK, EDIM, EDIM);
    // 7. g = rmsnorm(h2) * ff_norm_w (bf16)
    rmsnorm_bf16<<<NTOK, 256, 0, stream>>>(h2, fnw, g_b);
    // 8. u = g @ w1^T (bf16), then act = silu(u) * (g @ w3^T) in-place over ff1
    gemm256_nt<1><<<dim3(FF / 256, NTOK / 256), 512, 131072, stream>>>(
        g_b, w1_b, ff1, nullptr, NTOK, FF, EDIM);
    gemm256_nt<3><<<dim3(FF / 256, NTOK / 256), 512, 131072, stream>>>(
        g_b, w3_b, ff1, nullptr, NTOK, FF, EDIM);
    // 9. out = h2 + act @ w2^T  (fp32) -- N=2048, keep 128^2 tile
    gemm_nt<2><<<dim3(EDIM / 128, NTOK / 128), 256, 0, stream>>>(
        ff1, w2_b, out, h2, NTOK, EDIM, FF);
    (void)in_sizes; (void)n_in; (void)out_size; (void)ws_size;
}

// Round 3
// 1202.404 us; speedup vs baseline: 1.0182x; 1.0182x over previous
//
#include <hip/hip_runtime.h>
#include <hip/hip_bf16.h>
#include <cstdint>
#include <cstddef>

typedef __bf16 bf16;
typedef __bf16 bf16x2 __attribute__((ext_vector_type(2)));
typedef __bf16 bf16x4 __attribute__((ext_vector_type(4)));
typedef __bf16 bf16x8 __attribute__((ext_vector_type(8)));
typedef float f32x4 __attribute__((ext_vector_type(4)));
typedef float f32x16 __attribute__((ext_vector_type(16)));

// ---------------- constants ----------------
#define EDIM 2048
#define SEQ  2048
#define BATCH 2
#define NH   32
#define NKV  8
#define HD   64
#define FF   8192
#define NTOK 4096          // BATCH*SEQ
#define QKVN 3072          // EDIM + 2*512

// async 16B global -> LDS (lane-contiguous LDS layout required)
__device__ __forceinline__ void gld_lds16(const void* gp, void* lp) {
    __builtin_amdgcn_global_load_lds(
        (__attribute__((address_space(1))) void*)(gp),
        (__attribute__((address_space(3))) void*)(lp), 16, 0, 0);
}

// ---------------- fp32 -> bf16 convert ----------------
__global__ __launch_bounds__(256)
void cvt_f32_bf16(const float* __restrict__ in, bf16* __restrict__ out, long n4) {
    long i = (long)blockIdx.x * blockDim.x + threadIdx.x;
    long stride = (long)gridDim.x * blockDim.x;
    for (; i < n4; i += stride) {
        float4 v = ((const float4*)in)[i];
        bf16x4 o;
        o[0] = (bf16)v.x; o[1] = (bf16)v.y; o[2] = (bf16)v.z; o[3] = (bf16)v.w;
        ((bf16x4*)out)[i] = o;
    }
}

// ---------------- RMSNorm: fp32 row -> bf16 row ----------------
__global__ __launch_bounds__(256)
void rmsnorm_bf16(const float* __restrict__ x, const float* __restrict__ w,
                  bf16* __restrict__ out) {
    __shared__ float red[4];
    const int row = blockIdx.x;
    const long base = (long)row * EDIM;
    const int t = threadIdx.x;
    float4 v0 = *(const float4*)(x + base + t * 4);
    float4 v1 = *(const float4*)(x + base + 1024 + t * 4);
    float ss = v0.x*v0.x + v0.y*v0.y + v0.z*v0.z + v0.w*v0.w
             + v1.x*v1.x + v1.y*v1.y + v1.z*v1.z + v1.w*v1.w;
    #pragma unroll
    for (int off = 1; off < 64; off <<= 1) ss += __shfl_xor(ss, off, 64);
    if ((t & 63) == 0) red[t >> 6] = ss;
    __syncthreads();
    float tot = red[0] + red[1] + red[2] + red[3];
    float inv = rsqrtf(tot * (1.0f / EDIM) + 1e-5f);
    float4 w0 = *(const float4*)(w + t * 4);
    float4 w1 = *(const float4*)(w + 1024 + t * 4);
    bf16x4 o0, o1;
    o0[0] = (bf16)(v0.x * inv * w0.x); o0[1] = (bf16)(v0.y * inv * w0.y);
    o0[2] = (bf16)(v0.z * inv * w0.z); o0[3] = (bf16)(v0.w * inv * w0.w);
    o1[0] = (bf16)(v1.x * inv * w1.x); o1[1] = (bf16)(v1.y * inv * w1.y);
    o1[2] = (bf16)(v1.z * inv * w1.z); o1[3] = (bf16)(v1.w * inv * w1.w);
    *(bf16x4*)(out + base + t * 4) = o0;
    *(bf16x4*)(out + base + 1024 + t * 4) = o1;
}

// ---------------- NT GEMM: C[M,N] = A[M,K] * B[N,K]^T ----------------
// m97 structure: 128x128 tile, BK=32, 4 waves, 4x4 of mfma_f32_16x16x32_bf16
// EPI: 0 = f32 store, 1 = bf16 store, 2 = f32 store + f32 residual add,
//      3 = bf16 in-place: Cv[idx] = silu(Cv[idx]) * acc   (SwiGLU fuse)
template<int EPI>
__global__ __launch_bounds__(256, 2)
void gemm_nt(const bf16* __restrict__ A, const bf16* __restrict__ B,
             void* __restrict__ Cv, const float* __restrict__ res,
             int M, int N, int K) {
    __shared__ bf16 As[128 * 32];
    __shared__ bf16 Bs[128 * 32];
    const int tid = threadIdx.x;
    const int lane = tid & 63;
    const int wave = tid >> 6;
    const int wm = (wave >> 1) * 64;
    const int wn = (wave & 1) * 64;
    const int bm = blockIdx.y * 128;
    const int bn = blockIdx.x * 128;
    const int lrow = lane & 15;
    const int koff = (lane >> 4) * 8;

    f32x4 acc[4][4] = {};

    for (int k0 = 0; k0 < K; k0 += 32) {
        __syncthreads();
        #pragma unroll
        for (int t = 0; t < 2; ++t) {
            int c = tid + t * 256;           // 512 chunks of 16B per tile
            int r = c >> 2;
            int kc = (c & 3) * 8;
            gld_lds16(A + (long)(bm + r) * K + k0 + kc, As + c * 8);
            gld_lds16(B + (long)(bn + r) * K + k0 + kc, Bs + c * 8);
        }
        __syncthreads();
        bf16x8 af[4], bfr[4];
        #pragma unroll
        for (int t = 0; t < 4; ++t) {
            af[t]  = *(const bf16x8*)(As + (wm + t * 16 + lrow) * 32 + koff);
            bfr[t] = *(const bf16x8*)(Bs + (wn + t * 16 + lrow) * 32 + koff);
        }
        #pragma unroll
        for (int i = 0; i < 4; ++i)
            #pragma unroll
            for (int j = 0; j < 4; ++j)
                acc[i][j] = __builtin_amdgcn_mfma_f32_16x16x32_bf16(af[i], bfr[j], acc[i][j], 0, 0, 0);
    }

    const int row0 = bm + wm + (lane >> 4) * 4;
    const int col0 = bn + wn + (lane & 15);
    #pragma unroll
    for (int i = 0; i < 4; ++i) {
        #pragma unroll
        for (int j = 0; j < 4; ++j) {
            int col = col0 + j * 16;
            #pragma unroll
            for (int r = 0; r < 4; ++r) {
                long idx = (long)(row0 + i * 16 + r) * N + col;
                float v = acc[i][j][r];
                if (EPI == 0) {
                    ((float*)Cv)[idx] = v;
                } else if (EPI == 1) {
                    ((bf16*)Cv)[idx] = (bf16)v;
                } else if (EPI == 2) {
                    ((float*)Cv)[idx] = v + res[idx];
                } else {                       // EPI == 3: SwiGLU in-place
                    float u = (float)((bf16*)Cv)[idx];
                    float sl = u / (1.0f + __expf(-u));
                    ((bf16*)Cv)[idx] = (bf16)(sl * v);
                }
            }
        }
    }
}

// ---------------- RoPE prep: qkv bf16 [4096,3072] -> Q [B,H,S,64], K [B,KH,S,64] ----------------
// NOTE: Q is prescaled by 1/sqrt(HD) = 0.125 here (exact power-of-2 in bf16),
// so attn_fwd uses raw QK^T scores.
__global__ __launch_bounds__(256)
void rope_prep(const bf16* __restrict__ qkv, const float* __restrict__ fr,
               bf16* __restrict__ Qo, bf16* __restrict__ Ko) {
    const int row = blockIdx.x;            // b*SEQ + s
    const int b = row >> 11, s = row & 2047;
    const int t = threadIdx.x;
    const long rbase = (long)row * QKVN;
    #pragma unroll
    for (int i = 0; i < 4; ++i) {          // 1024 q pairs
        int p = t + i * 256;
        int hh = p >> 5, d = p & 31;
        bf16x2 xv = *(const bf16x2*)(qkv + rbase + hh * 64 + 2 * d);
        float x0 = (float)xv[0], x1 = (float)xv[1];
        float2 cs = *(const float2*)(fr + (long)(s * 32 + d) * 2);
        bf16x2 o;
        o[0] = (bf16)((x0 * cs.x - x1 * cs.y) * 0.125f);
        o[1] = (bf16)((x1 * cs.x + x0 * cs.y) * 0.125f);
        *(bf16x2*)(Qo + ((long)(b * NH + hh) * SEQ + s) * HD + 2 * d) = o;
    }
    {                                       // 256 k pairs
        int kh = t >> 5, d = t & 31;
        bf16x2 xv = *(const bf16x2*)(qkv + rbase + EDIM + kh * 64 + 2 * d);
        float x0 = (float)xv[0], x1 = (float)xv[1];
        float2 cs = *(const float2*)(fr + (long)(s * 32 + d) * 2);
        bf16x2 o;
        o[0] = (bf16)(x0 * cs.x - x1 * cs.y);
        o[1] = (bf16)(x1 * cs.x + x0 * cs.y);
        *(bf16x2*)(Ko + ((long)(b * NKV + kh) * SEQ + s) * HD + 2 * d) = o;
    }
}

// ---------------- V prep: transpose into [B,KH,S/64,hd=64,kk=64] bf16 tiles ----------------
__global__ __launch_bounds__(256)
void v_prep(const bf16* __restrict__ qkv, bf16* __restrict__ Vt) {
    __shared__ bf16 tile[64 * 72];          // +8 pad to break transpose conflicts
    const int blk = blockIdx.x;             // b*256 + kvh*32 + st
    const int b = blk >> 8;
    const int kvh = (blk >> 5) & 7;
    const int st = blk & 31;
    const int t = threadIdx.x;
    #pragma unroll
    for (int i = 0; i < 2; ++i) {
        int c = t + i * 256;                // 512 chunks
        int kk = c >> 3, hdo = (c & 7) * 8;
        bf16x8 v = *(const bf16x8*)(qkv + (long)(b * SEQ + st * 64 + kk) * QKVN + 2560 + kvh * 64 + hdo);
        *(bf16x8*)(tile + kk * 72 + hdo) = v;
    }
    __syncthreads();
    const long obase = ((long)(b * NKV + kvh) * 32 + st) * 4096;
    #pragma unroll
    for (int i = 0; i < 2; ++i) {
        int c = t + i * 256;
        int hd = c >> 3, ko = (c & 7) * 8;
        bf16x8 v;
        #pragma unroll
        for (int j = 0; j < 8; ++j) v[j] = tile[(ko + j) * 72 + hd];
        *(bf16x8*)(Vt + obase + hd * 64 + ko) = v;
    }
}

// ---------------- flash attention (causal, GQA 4:1), swapped-QK^T ----------------
// 4 waves/block, each wave owns 32 q-rows independently (no block barriers).
// mfma_f32_32x32x16_bf16, S^T = mfma(K,Q): each lane owns ONE q-row
// (col = lane&31) and 16 of 32 k-values in registers. Softmax = 15 in-reg
// fmax/adds + ONE __shfl_xor(.,32) per reduction (vs 64 shuffles before).
// P goes to PV through a tiny per-wave LDS buffer: 4x ds_write_b64
// (4 consecutive-k bf16 each, straight from the verified C layout) +
// 2x ds_read_b128 with a matched 16B-block XOR swizzle. P slot placement
// matches V's load pattern slot-for-slot (layout-permutation invariant).
// Q is prescaled by 0.125 in rope_prep.
__global__ __launch_bounds__(256, 4)
void attn_fwd(const bf16* __restrict__ Q, const bf16* __restrict__ K,
              const bf16* __restrict__ Vt, bf16* __restrict__ Out) {
    __shared__ bf16 Ps[4][32][40];           // per-wave P, 40-elem stride (80B = 5x16B)
    const int tid = threadIdx.x, lane = tid & 63, w = tid >> 6;
    const int qt = blockIdx.x;               // 128-row q tile
    const int bh = blockIdx.y;
    const int b = bh >> 5, h = bh & 31;
    const int kvh = h >> 2;
    const int ql = lane & 31;                // q-row owned by this lane
    const int hh = lane >> 5;                // lane half
    const int q3 = ql & 3;                   // LDS block-swizzle key
    const int q0 = qt * 128 + w * 32;        // wave's q base within seq
    const long qbase  = ((long)(b * NH + h) * SEQ + q0) * HD;
    const long kvbase = ((long)(b * NKV + kvh) * SEQ) * HD;
    bf16* Pw = &Ps[w][0][0];

    // Q fragments: qa[ds] = Q[q0+ql][ds*16 + hh*8 .. +8]  (B-operand layout)
    bf16x8 qa[4];
    #pragma unroll
    for (int ds = 0; ds < 4; ++ds)
        qa[ds] = *(const bf16x8*)(Q + qbase + (long)ql * HD + ds * 16 + hh * 8);

    f32x16 oacc[2] = {};                     // O^T accumulators (2 d-tiles of 32)
    float mi = -1e30f, li = 0.f;

    const int ntiles = qt * 4 + w + 1;       // causal trips over 32-wide kv tiles
    for (int kt = 0; kt < ntiles; ++kt) {
        const bf16* Kt = K + kvbase + (long)kt * (32 * HD);
        // S^T[k][q] = sum_d K[k][d] * Q[q][d]  (4 mfma over d-slices of 16)
        f32x16 s = {};
        #pragma unroll
        for (int ds = 0; ds < 4; ++ds) {
            bf16x8 ka = *(const bf16x8*)(Kt + ql * HD + ds * 16 + hh * 8);
            s = __builtin_amdgcn_mfma_f32_32x32x16_bf16(ka, qa[ds], s, 0, 0, 0);
        }
        if (kt == ntiles - 1) {
            // mask k > q : k_local(r) = (r&3) + 8*(r>>2) + 4*hh
            #pragma unroll
            for (int r = 0; r < 16; ++r) {
                int kk = kt * 32 + (r & 3) + 8 * (r >> 2) + 4 * hh;
                if (kk > q0 + ql) s[r] = -1e30f;
            }
        }
        // row max: 15 in-register + one cross-half shuffle
        float tmax = s[0];
        #pragma unroll
        for (int r = 1; r < 16; ++r) tmax = fmaxf(tmax, s[r]);
        tmax = fmaxf(tmax, __shfl_xor(tmax, 32, 64));
        // defer-max (T13, THR=0): rescale only when the running max grows
        if (!__all(tmax <= mi)) {
            float mnew = fmaxf(mi, tmax);
            float alpha = __expf(mi - mnew);
            li *= alpha;
            #pragma unroll
            for (int r = 0; r < 16; ++r) { oacc[0][r] *= alpha; oacc[1][r] *= alpha; }
            mi = mnew;
        }
        // p = exp(s - mi); write P[ql][k] as 4x b64 (4 consecutive k each),
        // 16B-block XOR swizzle: block' = (k>>3) ^ q3, elem = (k&7).
        // k(r) = (r&3) + 8*(r>>2) + 4*hh  ->  group g2 = r>>2 covers block g2,
        // elems (r&3) + 4*hh.
        float psum = 0.f;
        #pragma unroll
        for (int g2 = 0; g2 < 4; ++g2) {
            bf16x4 pw;
            #pragma unroll
            for (int j = 0; j < 4; ++j) {
                float p = __expf(s[g2 * 4 + j] - mi);
                psum += p;
                pw[j] = (bf16)p;
            }
            *(bf16x4*)(Pw + ql * 40 + ((g2 ^ q3) << 3) + 4 * hh) = pw;
        }
        psum += __shfl_xor(psum, 32, 64);
        li += psum;
        // B-fragments: p0 = P[ql][8*hh .. +8] (block hh), p1 = block 2+hh
        bf16x8 p0 = *(const bf16x8*)(Pw + ql * 40 + ((hh ^ q3) << 3));
        bf16x8 p1 = *(const bf16x8*)(Pw + ql * 40 + (((2 + hh) ^ q3) << 3));
        // PV: O^T[d][q] += V^T[d][k] * P^T[k][q]
        const bf16* Vtt = Vt + kvbase + (long)(kt >> 1) * 4096 + (kt & 1) * 32;
        #pragma unroll
        for (int t = 0; t < 2; ++t) {
            bf16x8 va0 = *(const bf16x8*)(Vtt + (t * 32 + ql) * 64 + hh * 8);
            bf16x8 va1 = *(const bf16x8*)(Vtt + (t * 32 + ql) * 64 + 16 + hh * 8);
            oacc[t] = __builtin_amdgcn_mfma_f32_32x32x16_bf16(va0, p0, oacc[t], 0, 0, 0);
            oacc[t] = __builtin_amdgcn_mfma_f32_32x32x16_bf16(va1, p1, oacc[t], 0, 0, 0);
        }
    }

    // epilogue: lane owns row q = q0+ql; d = t*32 + rg*8 + 4*hh + (0..3)
    float inv = 1.0f / li;
    const long obase = ((long)b * SEQ + q0 + ql) * EDIM + h * 64;
    #pragma unroll
    for (int t = 0; t < 2; ++t)
        #pragma unroll
        for (int rg = 0; rg < 4; ++rg) {
            bf16x4 o4;
            #pragma unroll
            for (int j = 0; j < 4; ++j) o4[j] = (bf16)(oacc[t][rg * 4 + j] * inv);
            *(bf16x4*)(Out + obase + t * 32 + rg * 8 + hh * 4) = o4;
        }
}

// ---------------- launcher ----------------
extern "C" void kernel_launch(void* const* d_in, const int* in_sizes, int n_in,
                              void* d_out, int out_size, void* d_ws, size_t ws_size,
                              hipStream_t stream) {
    const float* x    = (const float*)d_in[0];
    // d_in[1] = attention_mask (always causal tril; handled analytically)
    const float* fr   = (const float*)d_in[2];
    const float* wqkv = (const float*)d_in[3];
    const float* wo   = (const float*)d_in[4];
    const float* w1   = (const float*)d_in[5];
    const float* w2   = (const float*)d_in[6];
    const float* w3   = (const float*)d_in[7];
    const float* anw  = (const float*)d_in[8];
    const float* fnw  = (const float*)d_in[9];
    float* out = (float*)d_out;

    // ---- workspace budget (aliased layout), ~252 MiB ----
    const size_t SZ_WQKV = (size_t)QKVN * EDIM;     // 6291456
    const size_t SZ_WO   = (size_t)EDIM * EDIM;     // 4194304
    const size_t SZ_WFF  = (size_t)FF * EDIM;       // 16777216
    const size_t B_WQKV  = SZ_WQKV * 2;             // 12.6 MB
    const size_t B_WO    = SZ_WO * 2;               //  8.4 MB
    const size_t B_WFF   = SZ_WFF * 2;              // 33.6 MB
    const size_t B_HATTN = (size_t)NTOK * EDIM * 2; // 16.8 MB
    const size_t B_QKV   = (size_t)NTOK * QKVN * 2; // 25.2 MB
    const size_t B_SCR   = (size_t)NTOK * EDIM * 4; // 33.6 MB (h2 fp32; aliases Q/K/Vt)
    const size_t B_FF1   = (size_t)NTOK * FF * 2;   // 67.1 MB
    const size_t NEED = B_WQKV + B_WO + 3 * B_WFF + B_HATTN + B_QKV + B_SCR + B_FF1;
    if (ws_size < NEED) return;   // diagnostic: clean absmax-fail instead of GPU fault

    char* ws = (char*)d_ws;
    size_t off = 0;
    auto alloc = [&](size_t bytes) -> void* {
        void* p = ws + off;
        off += (bytes + 255) & ~(size_t)255;
        return p;
    };
    bf16* wqkv_b = (bf16*)alloc(B_WQKV);
    bf16* wo_b   = (bf16*)alloc(B_WO);
    bf16* w1_b   = (bf16*)alloc(B_WFF);
    bf16* w3_b   = (bf16*)alloc(B_WFF);
    bf16* w2_b   = (bf16*)alloc(B_WFF);
    bf16* h_attn = (bf16*)alloc(B_HATTN);           // h, then attn_out
    bf16* qkv_g  = (bf16*)alloc(B_QKV);             // qkv, then g
    char* scr    = (char*)alloc(B_SCR);             // Q/K/Vt region, then h2
    bf16* Qb  = (bf16*)scr;                                         // 16.8 MB
    bf16* Kb  = (bf16*)(scr + (size_t)BATCH * NH * SEQ * HD * 2);   //  4.2 MB
    bf16* Vtb = (bf16*)(scr + (size_t)BATCH * (NH + NKV) * SEQ * HD * 2); // 4.2 MB
    float* h2 = (float*)scr;                        // aliases Q/K/Vt (dead by then)
    bf16* ff1 = (bf16*)alloc(B_FF1);                // u, then act (in-place SwiGLU)
    bf16* g_b = qkv_g;                              // reuse (qkv dead after preps)

    // 1. weights -> bf16
    cvt_f32_bf16<<<512, 256, 0, stream>>>(wqkv, wqkv_b, (long)(SZ_WQKV / 4));
    cvt_f32_bf16<<<512, 256, 0, stream>>>(wo,   wo_b,   (long)(SZ_WO / 4));
    cvt_f32_bf16<<<512, 256, 0, stream>>>(w1,   w1_b,   (long)(SZ_WFF / 4));
    cvt_f32_bf16<<<512, 256, 0, stream>>>(w3,   w3_b,   (long)(SZ_WFF / 4));
    cvt_f32_bf16<<<512, 256, 0, stream>>>(w2,   w2_b,   (long)(SZ_WFF / 4));
    // 2. h = rmsnorm(x) * attn_norm_w  (bf16)
    rmsnorm_bf16<<<NTOK, 256, 0, stream>>>(x, anw, h_attn);
    // 3. qkv = h @ w_qkv^T  (bf16 out)
    gemm_nt<1><<<dim3(QKVN / 128, NTOK / 128), 256, 0, stream>>>(
        h_attn, wqkv_b, qkv_g, nullptr, NTOK, QKVN, EDIM);
    // 4. RoPE + layout prep (Q prescaled by 0.125)
    rope_prep<<<NTOK, 256, 0, stream>>>(qkv_g, fr, Qb, Kb);
    v_prep<<<BATCH * NKV * (SEQ / 64), 256, 0, stream>>>(qkv_g, Vtb);
    // 5. attention -> attn_out (bf16, [4096,2048]); 128 q-rows per block
    attn_fwd<<<dim3(SEQ / 128, BATCH * NH), 256, 0, stream>>>(Qb, Kb, Vtb, h_attn);
    // 6. h2 = x + attn_out @ w_o^T  (fp32; h2 aliases dead Q/K/Vt)
    gemm_nt<2><<<dim3(EDIM / 128, NTOK / 128), 256, 0, stream>>>(
        h_attn, wo_b, h2, x, NTOK, EDIM, EDIM);
    // 7. g = rmsnorm(h2) * ff_norm_w (bf16)
    rmsnorm_bf16<<<NTOK, 256, 0, stream>>>(h2, fnw, g_b);
    // 8. u = g @ w1^T (bf16), then act = silu(u) * (g @ w3^T) in-place over ff1
    gemm_nt<1><<<dim3(FF / 128, NTOK / 128), 256, 0, stream>>>(
        g_b, w1_b, ff1, nullptr, NTOK, FF, EDIM);
    gemm_nt<3><<<dim3(FF / 128, NTOK / 128), 256, 0, stream>>>(
        g_b, w3_b, ff1, nullptr, NTOK, FF, EDIM);
    // 9. out = h2 + act @ w2^T  (fp32)
    gemm_nt<2><<<dim3(EDIM / 128, NTOK / 128), 256, 0, stream>>>(
        ff1, w2_b, out, h2, NTOK, EDIM, FF);
    (void)in_sizes; (void)n_in; (void)out_size; (void)ws_size;
}

// Round 4
// 1118.752 us; speedup vs baseline: 1.0943x; 1.0748x over previous
//
#include <hip/hip_runtime.h>
#include <hip/hip_bf16.h>
#include <cstdint>
#include <cstddef>

typedef __bf16 bf16;
typedef __bf16 bf16x2 __attribute__((ext_vector_type(2)));
typedef __bf16 bf16x4 __attribute__((ext_vector_type(4)));
typedef __bf16 bf16x8 __attribute__((ext_vector_type(8)));
typedef float f32x4 __attribute__((ext_vector_type(4)));
typedef float f32x16 __attribute__((ext_vector_type(16)));

// ---------------- constants ----------------
#define EDIM 2048
#define SEQ  2048
#define BATCH 2
#define NH   32
#define NKV  8
#define HD   64
#define FF   8192
#define NTOK 4096          // BATCH*SEQ
#define QKVN 3072          // EDIM + 2*512

// async 16B global -> LDS (lane-contiguous LDS layout required)
__device__ __forceinline__ void gld_lds16(const void* gp, void* lp) {
    __builtin_amdgcn_global_load_lds(
        (__attribute__((address_space(1))) void*)(gp),
        (__attribute__((address_space(3))) void*)(lp), 16, 0, 0);
}

// ---------------- fp32 -> bf16 convert ----------------
__global__ __launch_bounds__(256)
void cvt_f32_bf16(const float* __restrict__ in, bf16* __restrict__ out, long n4) {
    long i = (long)blockIdx.x * blockDim.x + threadIdx.x;
    long stride = (long)gridDim.x * blockDim.x;
    for (; i < n4; i += stride) {
        float4 v = ((const float4*)in)[i];
        bf16x4 o;
        o[0] = (bf16)v.x; o[1] = (bf16)v.y; o[2] = (bf16)v.z; o[3] = (bf16)v.w;
        ((bf16x4*)out)[i] = o;
    }
}

// ---------------- RMSNorm: fp32 row -> bf16 row ----------------
__global__ __launch_bounds__(256)
void rmsnorm_bf16(const float* __restrict__ x, const float* __restrict__ w,
                  bf16* __restrict__ out) {
    __shared__ float red[4];
    const int row = blockIdx.x;
    const long base = (long)row * EDIM;
    const int t = threadIdx.x;
    float4 v0 = *(const float4*)(x + base + t * 4);
    float4 v1 = *(const float4*)(x + base + 1024 + t * 4);
    float ss = v0.x*v0.x + v0.y*v0.y + v0.z*v0.z + v0.w*v0.w
             + v1.x*v1.x + v1.y*v1.y + v1.z*v1.z + v1.w*v1.w;
    #pragma unroll
    for (int off = 1; off < 64; off <<= 1) ss += __shfl_xor(ss, off, 64);
    if ((t & 63) == 0) red[t >> 6] = ss;
    __syncthreads();
    float tot = red[0] + red[1] + red[2] + red[3];
    float inv = rsqrtf(tot * (1.0f / EDIM) + 1e-5f);
    float4 w0 = *(const float4*)(w + t * 4);
    float4 w1 = *(const float4*)(w + 1024 + t * 4);
    bf16x4 o0, o1;
    o0[0] = (bf16)(v0.x * inv * w0.x); o0[1] = (bf16)(v0.y * inv * w0.y);
    o0[2] = (bf16)(v0.z * inv * w0.z); o0[3] = (bf16)(v0.w * inv * w0.w);
    o1[0] = (bf16)(v1.x * inv * w1.x); o1[1] = (bf16)(v1.y * inv * w1.y);
    o1[2] = (bf16)(v1.z * inv * w1.z); o1[3] = (bf16)(v1.w * inv * w1.w);
    *(bf16x4*)(out + base + t * 4) = o0;
    *(bf16x4*)(out + base + 1024 + t * 4) = o1;
}

// ---------------- NT GEMM: C[M,N] = A[M,K] * B[N,K]^T ----------------
// m97 structure: 128x128 tile, BK=32, 4 waves, 4x4 of mfma_f32_16x16x32_bf16
// EPI: 0 = f32 store, 1 = bf16 store, 2 = f32 store + f32 residual add,
//      3 = bf16 in-place: Cv[idx] = silu(Cv[idx]) * acc   (SwiGLU fuse)
template<int EPI>
__global__ __launch_bounds__(256, 2)
void gemm_nt(const bf16* __restrict__ A, const bf16* __restrict__ B,
             void* __restrict__ Cv, const float* __restrict__ res,
             int M, int N, int K) {
    __shared__ bf16 As[128 * 32];
    __shared__ bf16 Bs[128 * 32];
    const int tid = threadIdx.x;
    const int lane = tid & 63;
    const int wave = tid >> 6;
    const int wm = (wave >> 1) * 64;
    const int wn = (wave & 1) * 64;
    const int bm = blockIdx.y * 128;
    const int bn = blockIdx.x * 128;
    const int lrow = lane & 15;
    const int koff = (lane >> 4) * 8;

    f32x4 acc[4][4] = {};

    for (int k0 = 0; k0 < K; k0 += 32) {
        __syncthreads();
        #pragma unroll
        for (int t = 0; t < 2; ++t) {
            int c = tid + t * 256;           // 512 chunks of 16B per tile
            int r = c >> 2;
            int kc = (c & 3) * 8;
            gld_lds16(A + (long)(bm + r) * K + k0 + kc, As + c * 8);
            gld_lds16(B + (long)(bn + r) * K + k0 + kc, Bs + c * 8);
        }
        __syncthreads();
        bf16x8 af[4], bfr[4];
        #pragma unroll
        for (int t = 0; t < 4; ++t) {
            af[t]  = *(const bf16x8*)(As + (wm + t * 16 + lrow) * 32 + koff);
            bfr[t] = *(const bf16x8*)(Bs + (wn + t * 16 + lrow) * 32 + koff);
        }
        #pragma unroll
        for (int i = 0; i < 4; ++i)
            #pragma unroll
            for (int j = 0; j < 4; ++j)
                acc[i][j] = __builtin_amdgcn_mfma_f32_16x16x32_bf16(af[i], bfr[j], acc[i][j], 0, 0, 0);
    }

    const int row0 = bm + wm + (lane >> 4) * 4;
    const int col0 = bn + wn + (lane & 15);
    #pragma unroll
    for (int i = 0; i < 4; ++i) {
        #pragma unroll
        for (int j = 0; j < 4; ++j) {
            int col = col0 + j * 16;
            #pragma unroll
            for (int r = 0; r < 4; ++r) {
                long idx = (long)(row0 + i * 16 + r) * N + col;
                float v = acc[i][j][r];
                if (EPI == 0) {
                    ((float*)Cv)[idx] = v;
                } else if (EPI == 1) {
                    ((bf16*)Cv)[idx] = (bf16)v;
                } else if (EPI == 2) {
                    ((float*)Cv)[idx] = v + res[idx];
                } else {                       // EPI == 3: SwiGLU in-place
                    float u = (float)((bf16*)Cv)[idx];
                    float sl = u / (1.0f + __expf(-u));
                    ((bf16*)Cv)[idx] = (bf16)(sl * v);
                }
            }
        }
    }
}

// ---------------- RoPE prep: qkv bf16 [4096,3072] -> Q [B,H,S,64], K [B,KH,S,64] ----------------
// NOTE: Q is prescaled by 1/sqrt(HD) = 0.125 here (exact power-of-2 in bf16),
// so attn_fwd uses raw QK^T scores.
__global__ __launch_bounds__(256)
void rope_prep(const bf16* __restrict__ qkv, const float* __restrict__ fr,
               bf16* __restrict__ Qo, bf16* __restrict__ Ko) {
    const int row = blockIdx.x;            // b*SEQ + s
    const int b = row >> 11, s = row & 2047;
    const int t = threadIdx.x;
    const long rbase = (long)row * QKVN;
    #pragma unroll
    for (int i = 0; i < 4; ++i) {          // 1024 q pairs
        int p = t + i * 256;
        int hh = p >> 5, d = p & 31;
        bf16x2 xv = *(const bf16x2*)(qkv + rbase + hh * 64 + 2 * d);
        float x0 = (float)xv[0], x1 = (float)xv[1];
        float2 cs = *(const float2*)(fr + (long)(s * 32 + d) * 2);
        bf16x2 o;
        o[0] = (bf16)((x0 * cs.x - x1 * cs.y) * 0.125f);
        o[1] = (bf16)((x1 * cs.x + x0 * cs.y) * 0.125f);
        *(bf16x2*)(Qo + ((long)(b * NH + hh) * SEQ + s) * HD + 2 * d) = o;
    }
    {                                       // 256 k pairs
        int kh = t >> 5, d = t & 31;
        bf16x2 xv = *(const bf16x2*)(qkv + rbase + EDIM + kh * 64 + 2 * d);
        float x0 = (float)xv[0], x1 = (float)xv[1];
        float2 cs = *(const float2*)(fr + (long)(s * 32 + d) * 2);
        bf16x2 o;
        o[0] = (bf16)(x0 * cs.x - x1 * cs.y);
        o[1] = (bf16)(x1 * cs.x + x0 * cs.y);
        *(bf16x2*)(Ko + ((long)(b * NKV + kh) * SEQ + s) * HD + 2 * d) = o;
    }
}

// ---------------- V prep: transpose into [B,KH,S/64,hd=64,kk=64] bf16 tiles ----------------
__global__ __launch_bounds__(256)
void v_prep(const bf16* __restrict__ qkv, bf16* __restrict__ Vt) {
    __shared__ bf16 tile[64 * 72];          // +8 pad to break transpose conflicts
    const int blk = blockIdx.x;             // b*256 + kvh*32 + st
    const int b = blk >> 8;
    const int kvh = (blk >> 5) & 7;
    const int st = blk & 31;
    const int t = threadIdx.x;
    #pragma unroll
    for (int i = 0; i < 2; ++i) {
        int c = t + i * 256;                // 512 chunks
        int kk = c >> 3, hdo = (c & 7) * 8;
        bf16x8 v = *(const bf16x8*)(qkv + (long)(b * SEQ + st * 64 + kk) * QKVN + 2560 + kvh * 64 + hdo);
        *(bf16x8*)(tile + kk * 72 + hdo) = v;
    }
    __syncthreads();
    const long obase = ((long)(b * NKV + kvh) * 32 + st) * 4096;
    #pragma unroll
    for (int i = 0; i < 2; ++i) {
        int c = t + i * 256;
        int hd = c >> 3, ko = (c & 7) * 8;
        bf16x8 v;
        #pragma unroll
        for (int j = 0; j < 8; ++j) v[j] = tile[(ko + j) * 72 + hd];
        *(bf16x8*)(Vt + obase + hd * 64 + ko) = v;
    }
}

// ---------------- flash attention (causal, GQA 4:1), swapped-QK^T ----------------
// 4 waves/block, each wave owns 32 q-rows independently (no block barriers).
// Grid = (bh, qt) so each CU draws mixed-qt blocks -> uniform per-CU work.
// Per iteration: 64 keys; ALL K+V fragment loads issued at the top (latency
// hidden under the two 32-key compute halves). Softmax per half: 15 in-reg
// fmax + ONE __shfl_xor(.,32); defer-max (T13) shared across halves.
// P -> PV via per-wave LDS with row-XOR swizzle sw=(ql^(ql>>3))&3.
// Q is prescaled by 0.125 in rope_prep.
__global__ __launch_bounds__(256, 3)
void attn_fwd(const bf16* __restrict__ Q, const bf16* __restrict__ K,
              const bf16* __restrict__ Vt, bf16* __restrict__ Out) {
    __shared__ bf16 Ps[4][32][40];           // per-wave P, 40-elem stride (80B = 5x16B)
    const int tid = threadIdx.x, lane = tid & 63, w = tid >> 6;
    const int bh = blockIdx.x;               // batch*head (fast grid dim for balance)
    const int qt = blockIdx.y;               // 128-row q tile
    const int b = bh >> 5, h = bh & 31;
    const int kvh = h >> 2;
    const int ql = lane & 31;                // q-row owned by this lane
    const int hh = lane >> 5;                // lane half
    const int sw = (ql ^ (ql >> 3)) & 3;     // LDS 16B-block swizzle key
    const int q0 = qt * 128 + w * 32;        // wave's q base within seq
    const int qmax = q0 + 31;
    const long qbase  = ((long)(b * NH + h) * SEQ + q0) * HD;
    const long kvbase = ((long)(b * NKV + kvh) * SEQ) * HD;
    bf16* Pw = &Ps[w][0][0];

    // Q fragments: qa[ds] = Q[q0+ql][ds*16 + hh*8 .. +8]  (B-operand layout)
    bf16x8 qa[4];
    #pragma unroll
    for (int ds = 0; ds < 4; ++ds)
        qa[ds] = *(const bf16x8*)(Q + qbase + (long)ql * HD + ds * 16 + hh * 8);

    f32x16 oacc[2] = {};                     // O^T accumulators (2 d-tiles of 32)
    float mi = -1e30f, li = 0.f;

    // 64-key tiles; last-tile second half may be skipped (fully masked)
    const int nt64 = qt * 2 + 1 + (w >> 1);
    for (int kt = 0; kt < nt64; ++kt) {
        const bf16* Kt  = K  + kvbase + (long)kt * (64 * HD);
        const bf16* Vtt = Vt + kvbase + (long)kt * 4096;
        // ---- batch-issue ALL loads for this 64-key tile ----
        bf16x8 ka[2][4], va[2][2][2];
        #pragma unroll
        for (int h2 = 0; h2 < 2; ++h2)
            #pragma unroll
            for (int ds = 0; ds < 4; ++ds)
                ka[h2][ds] = *(const bf16x8*)(Kt + (h2 * 32 + ql) * HD + ds * 16 + hh * 8);
        #pragma unroll
        for (int h2 = 0; h2 < 2; ++h2)
            #pragma unroll
            for (int t = 0; t < 2; ++t)
                #pragma unroll
                for (int c = 0; c < 2; ++c)
                    va[h2][t][c] = *(const bf16x8*)(Vtt + (t * 32 + ql) * 64 + h2 * 32 + c * 16 + hh * 8);
        const bool lastt = (kt == nt64 - 1);
        #pragma unroll
        for (int h2 = 0; h2 < 2; ++h2) {
            if (h2 == 1 && kt * 64 + 32 > qmax) break;   // wave-uniform skip
            // S^T[k][q] over 32 keys (4 mfma over d-slices of 16)
            f32x16 s = {};
            #pragma unroll
            for (int ds = 0; ds < 4; ++ds)
                s = __builtin_amdgcn_mfma_f32_32x32x16_bf16(ka[h2][ds], qa[ds], s, 0, 0, 0);
            if (lastt) {
                #pragma unroll
                for (int r = 0; r < 16; ++r) {
                    int kk = kt * 64 + h2 * 32 + (r & 3) + 8 * (r >> 2) + 4 * hh;
                    if (kk > q0 + ql) s[r] = -1e30f;
                }
            }
            // row max: 15 in-register + one cross-half shuffle
            float tmax = s[0];
            #pragma unroll
            for (int r = 1; r < 16; ++r) tmax = fmaxf(tmax, s[r]);
            tmax = fmaxf(tmax, __shfl_xor(tmax, 32, 64));
            // defer-max: rescale only when the running max grows
            if (!__all(tmax <= mi)) {
                float mnew = fmaxf(mi, tmax);
                float alpha = __expf(mi - mnew);
                li *= alpha;
                #pragma unroll
                for (int r = 0; r < 16; ++r) { oacc[0][r] *= alpha; oacc[1][r] *= alpha; }
                mi = mnew;
            }
            // p = exp(s - mi); P[ql][k] as 4x b64, swizzled 16B blocks
            float psum = 0.f;
            #pragma unroll
            for (int g2 = 0; g2 < 4; ++g2) {
                bf16x4 pw;
                #pragma unroll
                for (int j = 0; j < 4; ++j) {
                    float p = __expf(s[g2 * 4 + j] - mi);
                    psum += p;
                    pw[j] = (bf16)p;
                }
                *(bf16x4*)(Pw + ql * 40 + ((g2 ^ sw) << 3) + 4 * hh) = pw;
            }
            psum += __shfl_xor(psum, 32, 64);
            li += psum;
            // B-fragments from swizzled LDS
            bf16x8 p0 = *(const bf16x8*)(Pw + ql * 40 + ((hh ^ sw) << 3));
            bf16x8 p1 = *(const bf16x8*)(Pw + ql * 40 + (((2 + hh) ^ sw) << 3));
            // PV: O^T[d][q] += V^T[d][k] * P^T[k][q]
            #pragma unroll
            for (int t = 0; t < 2; ++t) {
                oacc[t] = __builtin_amdgcn_mfma_f32_32x32x16_bf16(va[h2][t][0], p0, oacc[t], 0, 0, 0);
                oacc[t] = __builtin_amdgcn_mfma_f32_32x32x16_bf16(va[h2][t][1], p1, oacc[t], 0, 0, 0);
            }
        }
    }

    // epilogue: lane owns row q = q0+ql; d = t*32 + rg*8 + 4*hh + (0..3)
    float inv = 1.0f / li;
    const long obase = ((long)b * SEQ + q0 + ql) * EDIM + h * 64;
    #pragma unroll
    for (int t = 0; t < 2; ++t)
        #pragma unroll
        for (int rg = 0; rg < 4; ++rg) {
            bf16x4 o4;
            #pragma unroll
            for (int j = 0; j < 4; ++j) o4[j] = (bf16)(oacc[t][rg * 4 + j] * inv);
            *(bf16x4*)(Out + obase + t * 32 + rg * 8 + hh * 4) = o4;
        }
}

// ---------------- launcher ----------------
extern "C" void kernel_launch(void* const* d_in, const int* in_sizes, int n_in,
                              void* d_out, int out_size, void* d_ws, size_t ws_size,
                              hipStream_t stream) {
    const float* x    = (const float*)d_in[0];
    // d_in[1] = attention_mask (always causal tril; handled analytically)
    const float* fr   = (const float*)d_in[2];
    const float* wqkv = (const float*)d_in[3];
    const float* wo   = (const float*)d_in[4];
    const float* w1   = (const float*)d_in[5];
    const float* w2   = (const float*)d_in[6];
    const float* w3   = (const float*)d_in[7];
    const float* anw  = (const float*)d_in[8];
    const float* fnw  = (const float*)d_in[9];
    float* out = (float*)d_out;

    // ---- workspace budget (aliased layout), ~252 MiB ----
    const size_t SZ_WQKV = (size_t)QKVN * EDIM;     // 6291456
    const size_t SZ_WO   = (size_t)EDIM * EDIM;     // 4194304
    const size_t SZ_WFF  = (size_t)FF * EDIM;       // 16777216
    const size_t B_WQKV  = SZ_WQKV * 2;             // 12.6 MB
    const size_t B_WO    = SZ_WO * 2;               //  8.4 MB
    const size_t B_WFF   = SZ_WFF * 2;              // 33.6 MB
    const size_t B_HATTN = (size_t)NTOK * EDIM * 2; // 16.8 MB
    const size_t B_QKV   = (size_t)NTOK * QKVN * 2; // 25.2 MB
    const size_t B_SCR   = (size_t)NTOK * EDIM * 4; // 33.6 MB (h2 fp32; aliases Q/K/Vt)
    const size_t B_FF1   = (size_t)NTOK * FF * 2;   // 67.1 MB
    const size_t NEED = B_WQKV + B_WO + 3 * B_WFF + B_HATTN + B_QKV + B_SCR + B_FF1;
    if (ws_size < NEED) return;   // diagnostic: clean absmax-fail instead of GPU fault

    char* ws = (char*)d_ws;
    size_t off = 0;
    auto alloc = [&](size_t bytes) -> void* {
        void* p = ws + off;
        off += (bytes + 255) & ~(size_t)255;
        return p;
    };
    bf16* wqkv_b = (bf16*)alloc(B_WQKV);
    bf16* wo_b   = (bf16*)alloc(B_WO);
    bf16* w1_b   = (bf16*)alloc(B_WFF);
    bf16* w3_b   = (bf16*)alloc(B_WFF);
    bf16* w2_b   = (bf16*)alloc(B_WFF);
    bf16* h_attn = (bf16*)alloc(B_HATTN);           // h, then attn_out
    bf16* qkv_g  = (bf16*)alloc(B_QKV);             // qkv, then g
    char* scr    = (char*)alloc(B_SCR);             // Q/K/Vt region, then h2
    bf16* Qb  = (bf16*)scr;                                         // 16.8 MB
    bf16* Kb  = (bf16*)(scr + (size_t)BATCH * NH * SEQ * HD * 2);   //  4.2 MB
    bf16* Vtb = (bf16*)(scr + (size_t)BATCH * (NH + NKV) * SEQ * HD * 2); // 4.2 MB
    float* h2 = (float*)scr;                        // aliases Q/K/Vt (dead by then)
    bf16* ff1 = (bf16*)alloc(B_FF1);                // u, then act (in-place SwiGLU)
    bf16* g_b = qkv_g;                              // reuse (qkv dead after preps)

    // 1. weights -> bf16
    cvt_f32_bf16<<<512, 256, 0, stream>>>(wqkv, wqkv_b, (long)(SZ_WQKV / 4));
    cvt_f32_bf16<<<512, 256, 0, stream>>>(wo,   wo_b,   (long)(SZ_WO / 4));
    cvt_f32_bf16<<<512, 256, 0, stream>>>(w1,   w1_b,   (long)(SZ_WFF / 4));
    cvt_f32_bf16<<<512, 256, 0, stream>>>(w3,   w3_b,   (long)(SZ_WFF / 4));
    cvt_f32_bf16<<<512, 256, 0, stream>>>(w2,   w2_b,   (long)(SZ_WFF / 4));
    // 2. h = rmsnorm(x) * attn_norm_w  (bf16)
    rmsnorm_bf16<<<NTOK, 256, 0, stream>>>(x, anw, h_attn);
    // 3. qkv = h @ w_qkv^T  (bf16 out)
    gemm_nt<1><<<dim3(QKVN / 128, NTOK / 128), 256, 0, stream>>>(
        h_attn, wqkv_b, qkv_g, nullptr, NTOK, QKVN, EDIM);
    // 4. RoPE + layout prep (Q prescaled by 0.125)
    rope_prep<<<NTOK, 256, 0, stream>>>(qkv_g, fr, Qb, Kb);
    v_prep<<<BATCH * NKV * (SEQ / 64), 256, 0, stream>>>(qkv_g, Vtb);
    // 5. attention -> attn_out (bf16, [4096,2048]); grid (bh, qt) for balance
    attn_fwd<<<dim3(BATCH * NH, SEQ / 128), 256, 0, stream>>>(Qb, Kb, Vtb, h_attn);
    // 6. h2 = x + attn_out @ w_o^T  (fp32; h2 aliases dead Q/K/Vt)
    gemm_nt<2><<<dim3(EDIM / 128, NTOK / 128), 256, 0, stream>>>(
        h_attn, wo_b, h2, x, NTOK, EDIM, EDIM);
    // 7. g = rmsnorm(h2) * ff_norm_w (bf16)
    rmsnorm_bf16<<<NTOK, 256, 0, stream>>>(h2, fnw, g_b);
    // 8. u = g @ w1^T (bf16), then act = silu(u) * (g @ w3^T) in-place over ff1
    gemm_nt<1><<<dim3(FF / 128, NTOK / 128), 256, 0, stream>>>(
        g_b, w1_b, ff1, nullptr, NTOK, FF, EDIM);
    gemm_nt<3><<<dim3(FF / 128, NTOK / 128), 256, 0, stream>>>(
        g_b, w3_b, ff1, nullptr, NTOK, FF, EDIM);
    // 9. out = h2 + act @ w2^T  (fp32)
    gemm_nt<2><<<dim3(EDIM / 128, NTOK / 128), 256, 0, stream>>>(
        ff1, w2_b, out, h2, NTOK, EDIM, FF);
    (void)in_sizes; (void)n_in; (void)out_size; (void)ws_size;
}

// Round 5
// 1114.292 us; speedup vs baseline: 1.0987x; 1.0040x over previous
//
#include <hip/hip_runtime.h>
#include <hip/hip_bf16.h>
#include <cstdint>
#include <cstddef>

typedef __bf16 bf16;
typedef __bf16 bf16x2 __attribute__((ext_vector_type(2)));
typedef __bf16 bf16x4 __attribute__((ext_vector_type(4)));
typedef __bf16 bf16x8 __attribute__((ext_vector_type(8)));
typedef float f32x4 __attribute__((ext_vector_type(4)));
typedef float f32x16 __attribute__((ext_vector_type(16)));

// ---------------- constants ----------------
#define EDIM 2048
#define SEQ  2048
#define BATCH 2
#define NH   32
#define NKV  8
#define HD   64
#define FF   8192
#define NTOK 4096          // BATCH*SEQ
#define QKVN 3072          // EDIM + 2*512

// async 16B global -> LDS (lane-contiguous LDS layout required)
__device__ __forceinline__ void gld_lds16(const void* gp, void* lp) {
    __builtin_amdgcn_global_load_lds(
        (__attribute__((address_space(1))) void*)(gp),
        (__attribute__((address_space(3))) void*)(lp), 16, 0, 0);
}

// ---------------- fp32 -> bf16 convert ----------------
__global__ __launch_bounds__(256)
void cvt_f32_bf16(const float* __restrict__ in, bf16* __restrict__ out, long n4) {
    long i = (long)blockIdx.x * blockDim.x + threadIdx.x;
    long stride = (long)gridDim.x * blockDim.x;
    for (; i < n4; i += stride) {
        float4 v = ((const float4*)in)[i];
        bf16x4 o;
        o[0] = (bf16)v.x; o[1] = (bf16)v.y; o[2] = (bf16)v.z; o[3] = (bf16)v.w;
        ((bf16x4*)out)[i] = o;
    }
}

// ---------------- RMSNorm: fp32 row -> bf16 row ----------------
__global__ __launch_bounds__(256)
void rmsnorm_bf16(const float* __restrict__ x, const float* __restrict__ w,
                  bf16* __restrict__ out) {
    __shared__ float red[4];
    const int row = blockIdx.x;
    const long base = (long)row * EDIM;
    const int t = threadIdx.x;
    float4 v0 = *(const float4*)(x + base + t * 4);
    float4 v1 = *(const float4*)(x + base + 1024 + t * 4);
    float ss = v0.x*v0.x + v0.y*v0.y + v0.z*v0.z + v0.w*v0.w
             + v1.x*v1.x + v1.y*v1.y + v1.z*v1.z + v1.w*v1.w;
    #pragma unroll
    for (int off = 1; off < 64; off <<= 1) ss += __shfl_xor(ss, off, 64);
    if ((t & 63) == 0) red[t >> 6] = ss;
    __syncthreads();
    float tot = red[0] + red[1] + red[2] + red[3];
    float inv = rsqrtf(tot * (1.0f / EDIM) + 1e-5f);
    float4 w0 = *(const float4*)(w + t * 4);
    float4 w1 = *(const float4*)(w + 1024 + t * 4);
    bf16x4 o0, o1;
    o0[0] = (bf16)(v0.x * inv * w0.x); o0[1] = (bf16)(v0.y * inv * w0.y);
    o0[2] = (bf16)(v0.z * inv * w0.z); o0[3] = (bf16)(v0.w * inv * w0.w);
    o1[0] = (bf16)(v1.x * inv * w1.x); o1[1] = (bf16)(v1.y * inv * w1.y);
    o1[2] = (bf16)(v1.z * inv * w1.z); o1[3] = (bf16)(v1.w * inv * w1.w);
    *(bf16x4*)(out + base + t * 4) = o0;
    *(bf16x4*)(out + base + 1024 + t * 4) = o1;
}

// ---------------- NT GEMM: C[M,N] = A[M,K] * B[N,K]^T ----------------
// m97 structure: 128x128 tile, BK=32, 4 waves, 4x4 of mfma_f32_16x16x32_bf16
// Block remap (T1): XCD-chunk (bijective, nwg%8==0) then 8x8 supertile so the
// ~64 concurrent blocks per XCD form one compact 8x8 tile region -> per-XCD L2
// holds the A/B panels instead of spanning all of N (FETCH was 3.2x ideal).
// EPI: 0 = f32 store, 1 = bf16 store, 2 = f32 store + f32 residual add,
//      3 = bf16 in-place: Cv[idx] = silu(Cv[idx]) * acc   (SwiGLU fuse)
template<int EPI>
__global__ __launch_bounds__(256, 2)
void gemm_nt(const bf16* __restrict__ A, const bf16* __restrict__ B,
             void* __restrict__ Cv, const float* __restrict__ res,
             int M, int N, int K) {
    __shared__ bf16 As[128 * 32];
    __shared__ bf16 Bs[128 * 32];
    const int tid = threadIdx.x;
    const int lane = tid & 63;
    const int wave = tid >> 6;
    const int wm = (wave >> 1) * 64;
    const int wn = (wave & 1) * 64;

    // ---- block remap: XCD chunk + 8x8 supertile ----
    int gx = gridDim.x, gy = gridDim.y;
    int bx = blockIdx.x, by = blockIdx.y;
    int nwg = gx * gy;
    if (((nwg & 63) | (gx & 7) | (gy & 7)) == 0) {
        int l = bx + gx * by;
        int nl = (l & 7) * (nwg >> 3) + (l >> 3);   // XCD gets contiguous range
        int s = nl >> 6, r = nl & 63;               // 8x8 supertile of blocks
        int spr = gx >> 3;                          // supertiles per row
        bx = (s % spr) * 8 + (r & 7);
        by = (s / spr) * 8 + (r >> 3);
    }
    const int bm = by * 128;
    const int bn = bx * 128;
    const int lrow = lane & 15;
    const int koff = (lane >> 4) * 8;

    f32x4 acc[4][4] = {};

    for (int k0 = 0; k0 < K; k0 += 32) {
        __syncthreads();
        #pragma unroll
        for (int t = 0; t < 2; ++t) {
            int c = tid + t * 256;           // 512 chunks of 16B per tile
            int r = c >> 2;
            int kc = (c & 3) * 8;
            gld_lds16(A + (long)(bm + r) * K + k0 + kc, As + c * 8);
            gld_lds16(B + (long)(bn + r) * K + k0 + kc, Bs + c * 8);
        }
        __syncthreads();
        bf16x8 af[4], bfr[4];
        #pragma unroll
        for (int t = 0; t < 4; ++t) {
            af[t]  = *(const bf16x8*)(As + (wm + t * 16 + lrow) * 32 + koff);
            bfr[t] = *(const bf16x8*)(Bs + (wn + t * 16 + lrow) * 32 + koff);
        }
        #pragma unroll
        for (int i = 0; i < 4; ++i)
            #pragma unroll
            for (int j = 0; j < 4; ++j)
                acc[i][j] = __builtin_amdgcn_mfma_f32_16x16x32_bf16(af[i], bfr[j], acc[i][j], 0, 0, 0);
    }

    const int row0 = bm + wm + (lane >> 4) * 4;
    const int col0 = bn + wn + (lane & 15);
    #pragma unroll
    for (int i = 0; i < 4; ++i) {
        #pragma unroll
        for (int j = 0; j < 4; ++j) {
            int col = col0 + j * 16;
            #pragma unroll
            for (int r = 0; r < 4; ++r) {
                long idx = (long)(row0 + i * 16 + r) * N + col;
                float v = acc[i][j][r];
                if (EPI == 0) {
                    ((float*)Cv)[idx] = v;
                } else if (EPI == 1) {
                    ((bf16*)Cv)[idx] = (bf16)v;
                } else if (EPI == 2) {
                    ((float*)Cv)[idx] = v + res[idx];
                } else {                       // EPI == 3: SwiGLU in-place
                    float u = (float)((bf16*)Cv)[idx];
                    float sl = u / (1.0f + __expf(-u));
                    ((bf16*)Cv)[idx] = (bf16)(sl * v);
                }
            }
        }
    }
}

// ---------------- RoPE prep: qkv bf16 [4096,3072] -> Q [B,H,S,64], K [B,KH,S,64] ----------------
// NOTE: Q is prescaled by 1/sqrt(HD) = 0.125 here (exact power-of-2 in bf16),
// so attn_fwd uses raw QK^T scores.
__global__ __launch_bounds__(256)
void rope_prep(const bf16* __restrict__ qkv, const float* __restrict__ fr,
               bf16* __restrict__ Qo, bf16* __restrict__ Ko) {
    const int row = blockIdx.x;            // b*SEQ + s
    const int b = row >> 11, s = row & 2047;
    const int t = threadIdx.x;
    const long rbase = (long)row * QKVN;
    #pragma unroll
    for (int i = 0; i < 4; ++i) {          // 1024 q pairs
        int p = t + i * 256;
        int hh = p >> 5, d = p & 31;
        bf16x2 xv = *(const bf16x2*)(qkv + rbase + hh * 64 + 2 * d);
        float x0 = (float)xv[0], x1 = (float)xv[1];
        float2 cs = *(const float2*)(fr + (long)(s * 32 + d) * 2);
        bf16x2 o;
        o[0] = (bf16)((x0 * cs.x - x1 * cs.y) * 0.125f);
        o[1] = (bf16)((x1 * cs.x + x0 * cs.y) * 0.125f);
        *(bf16x2*)(Qo + ((long)(b * NH + hh) * SEQ + s) * HD + 2 * d) = o;
    }
    {                                       // 256 k pairs
        int kh = t >> 5, d = t & 31;
        bf16x2 xv = *(const bf16x2*)(qkv + rbase + EDIM + kh * 64 + 2 * d);
        float x0 = (float)xv[0], x1 = (float)xv[1];
        float2 cs = *(const float2*)(fr + (long)(s * 32 + d) * 2);
        bf16x2 o;
        o[0] = (bf16)(x0 * cs.x - x1 * cs.y);
        o[1] = (bf16)(x1 * cs.x + x0 * cs.y);
        *(bf16x2*)(Ko + ((long)(b * NKV + kh) * SEQ + s) * HD + 2 * d) = o;
    }
}

// ---------------- V prep: transpose into [B,KH,S/64,hd=64,kk=64] bf16 tiles ----------------
__global__ __launch_bounds__(256)
void v_prep(const bf16* __restrict__ qkv, bf16* __restrict__ Vt) {
    __shared__ bf16 tile[64 * 72];          // +8 pad to break transpose conflicts
    const int blk = blockIdx.x;             // b*256 + kvh*32 + st
    const int b = blk >> 8;
    const int kvh = (blk >> 5) & 7;
    const int st = blk & 31;
    const int t = threadIdx.x;
    #pragma unroll
    for (int i = 0; i < 2; ++i) {
        int c = t + i * 256;                // 512 chunks
        int kk = c >> 3, hdo = (c & 7) * 8;
        bf16x8 v = *(const bf16x8*)(qkv + (long)(b * SEQ + st * 64 + kk) * QKVN + 2560 + kvh * 64 + hdo);
        *(bf16x8*)(tile + kk * 72 + hdo) = v;
    }
    __syncthreads();
    const long obase = ((long)(b * NKV + kvh) * 32 + st) * 4096;
    #pragma unroll
    for (int i = 0; i < 2; ++i) {
        int c = t + i * 256;
        int hd = c >> 3, ko = (c & 7) * 8;
        bf16x8 v;
        #pragma unroll
        for (int j = 0; j < 8; ++j) v[j] = tile[(ko + j) * 72 + hd];
        *(bf16x8*)(Vt + obase + hd * 64 + ko) = v;
    }
}

// ---------------- flash attention (causal, GQA 4:1), swapped-QK^T ----------------
// 4 waves/block, each wave owns 32 q-rows independently (no block barriers).
// Grid = (bh, qt) so each CU draws mixed-qt blocks -> uniform per-CU work.
// Per iteration: 64 keys; ALL K+V fragment loads issued at the top (latency
// hidden under the two 32-key compute halves). Softmax per half: 15 in-reg
// fmax + ONE __shfl_xor(.,32); defer-max (T13) shared across halves.
// P -> PV via per-wave LDS with row-XOR swizzle sw=(ql^(ql>>3))&3.
// Q is prescaled by 0.125 in rope_prep.
__global__ __launch_bounds__(256, 3)
void attn_fwd(const bf16* __restrict__ Q, const bf16* __restrict__ K,
              const bf16* __restrict__ Vt, bf16* __restrict__ Out) {
    __shared__ bf16 Ps[4][32][40];           // per-wave P, 40-elem stride (80B = 5x16B)
    const int tid = threadIdx.x, lane = tid & 63, w = tid >> 6;
    const int bh = blockIdx.x;               // batch*head (fast grid dim for balance)
    const int qt = blockIdx.y;               // 128-row q tile
    const int b = bh >> 5, h = bh & 31;
    const int kvh = h >> 2;
    const int ql = lane & 31;                // q-row owned by this lane
    const int hh = lane >> 5;                // lane half
    const int sw = (ql ^ (ql >> 3)) & 3;     // LDS 16B-block swizzle key
    const int q0 = qt * 128 + w * 32;        // wave's q base within seq
    const int qmax = q0 + 31;
    const long qbase  = ((long)(b * NH + h) * SEQ + q0) * HD;
    const long kvbase = ((long)(b * NKV + kvh) * SEQ) * HD;
    bf16* Pw = &Ps[w][0][0];

    // Q fragments: qa[ds] = Q[q0+ql][ds*16 + hh*8 .. +8]  (B-operand layout)
    bf16x8 qa[4];
    #pragma unroll
    for (int ds = 0; ds < 4; ++ds)
        qa[ds] = *(const bf16x8*)(Q + qbase + (long)ql * HD + ds * 16 + hh * 8);

    f32x16 oacc[2] = {};                     // O^T accumulators (2 d-tiles of 32)
    float mi = -1e30f, li = 0.f;

    // 64-key tiles; last-tile second half may be skipped (fully masked)
    const int nt64 = qt * 2 + 1 + (w >> 1);
    for (int kt = 0; kt < nt64; ++kt) {
        const bf16* Kt  = K  + kvbase + (long)kt * (64 * HD);
        const bf16* Vtt = Vt + kvbase + (long)kt * 4096;
        // ---- batch-issue ALL loads for this 64-key tile ----
        bf16x8 ka[2][4], va[2][2][2];
        #pragma unroll
        for (int h2 = 0; h2 < 2; ++h2)
            #pragma unroll
            for (int ds = 0; ds < 4; ++ds)
                ka[h2][ds] = *(const bf16x8*)(Kt + (h2 * 32 + ql) * HD + ds * 16 + hh * 8);
        #pragma unroll
        for (int h2 = 0; h2 < 2; ++h2)
            #pragma unroll
            for (int t = 0; t < 2; ++t)
                #pragma unroll
                for (int c = 0; c < 2; ++c)
                    va[h2][t][c] = *(const bf16x8*)(Vtt + (t * 32 + ql) * 64 + h2 * 32 + c * 16 + hh * 8);
        const bool lastt = (kt == nt64 - 1);
        #pragma unroll
        for (int h2 = 0; h2 < 2; ++h2) {
            if (h2 == 1 && kt * 64 + 32 > qmax) break;   // wave-uniform skip
            // S^T[k][q] over 32 keys (4 mfma over d-slices of 16)
            f32x16 s = {};
            #pragma unroll
            for (int ds = 0; ds < 4; ++ds)
                s = __builtin_amdgcn_mfma_f32_32x32x16_bf16(ka[h2][ds], qa[ds], s, 0, 0, 0);
            if (lastt) {
                #pragma unroll
                for (int r = 0; r < 16; ++r) {
                    int kk = kt * 64 + h2 * 32 + (r & 3) + 8 * (r >> 2) + 4 * hh;
                    if (kk > q0 + ql) s[r] = -1e30f;
                }
            }
            // row max: 15 in-register + one cross-half shuffle
            float tmax = s[0];
            #pragma unroll
            for (int r = 1; r < 16; ++r) tmax = fmaxf(tmax, s[r]);
            tmax = fmaxf(tmax, __shfl_xor(tmax, 32, 64));
            // defer-max: rescale only when the running max grows
            if (!__all(tmax <= mi)) {
                float mnew = fmaxf(mi, tmax);
                float alpha = __expf(mi - mnew);
                li *= alpha;
                #pragma unroll
                for (int r = 0; r < 16; ++r) { oacc[0][r] *= alpha; oacc[1][r] *= alpha; }
                mi = mnew;
            }
            // p = exp(s - mi); P[ql][k] as 4x b64, swizzled 16B blocks
            float psum = 0.f;
            #pragma unroll
            for (int g2 = 0; g2 < 4; ++g2) {
                bf16x4 pw;
                #pragma unroll
                for (int j = 0; j < 4; ++j) {
                    float p = __expf(s[g2 * 4 + j] - mi);
                    psum += p;
                    pw[j] = (bf16)p;
                }
                *(bf16x4*)(Pw + ql * 40 + ((g2 ^ sw) << 3) + 4 * hh) = pw;
            }
            psum += __shfl_xor(psum, 32, 64);
            li += psum;
            // B-fragments from swizzled LDS
            bf16x8 p0 = *(const bf16x8*)(Pw + ql * 40 + ((hh ^ sw) << 3));
            bf16x8 p1 = *(const bf16x8*)(Pw + ql * 40 + (((2 + hh) ^ sw) << 3));
            // PV: O^T[d][q] += V^T[d][k] * P^T[k][q]
            #pragma unroll
            for (int t = 0; t < 2; ++t) {
                oacc[t] = __builtin_amdgcn_mfma_f32_32x32x16_bf16(va[h2][t][0], p0, oacc[t], 0, 0, 0);
                oacc[t] = __builtin_amdgcn_mfma_f32_32x32x16_bf16(va[h2][t][1], p1, oacc[t], 0, 0, 0);
            }
        }
    }

    // epilogue: lane owns row q = q0+ql; d = t*32 + rg*8 + 4*hh + (0..3)
    float inv = 1.0f / li;
    const long obase = ((long)b * SEQ + q0 + ql) * EDIM + h * 64;
    #pragma unroll
    for (int t = 0; t < 2; ++t)
        #pragma unroll
        for (int rg = 0; rg < 4; ++rg) {
            bf16x4 o4;
            #pragma unroll
            for (int j = 0; j < 4; ++j) o4[j] = (bf16)(oacc[t][rg * 4 + j] * inv);
            *(bf16x4*)(Out + obase + t * 32 + rg * 8 + hh * 4) = o4;
        }
}

// ---------------- launcher ----------------
extern "C" void kernel_launch(void* const* d_in, const int* in_sizes, int n_in,
                              void* d_out, int out_size, void* d_ws, size_t ws_size,
                              hipStream_t stream) {
    const float* x    = (const float*)d_in[0];
    // d_in[1] = attention_mask (always causal tril; handled analytically)
    const float* fr   = (const float*)d_in[2];
    const float* wqkv = (const float*)d_in[3];
    const float* wo   = (const float*)d_in[4];
    const float* w1   = (const float*)d_in[5];
    const float* w2   = (const float*)d_in[6];
    const float* w3   = (const float*)d_in[7];
    const float* anw  = (const float*)d_in[8];
    const float* fnw  = (const float*)d_in[9];
    float* out = (float*)d_out;

    // ---- workspace budget (aliased layout), ~252 MiB ----
    const size_t SZ_WQKV = (size_t)QKVN * EDIM;     // 6291456
    const size_t SZ_WO   = (size_t)EDIM * EDIM;     // 4194304
    const size_t SZ_WFF  = (size_t)FF * EDIM;       // 16777216
    const size_t B_WQKV  = SZ_WQKV * 2;             // 12.6 MB
    const size_t B_WO    = SZ_WO * 2;               //  8.4 MB
    const size_t B_WFF   = SZ_WFF * 2;              // 33.6 MB
    const size_t B_HATTN = (size_t)NTOK * EDIM * 2; // 16.8 MB
    const size_t B_QKV   = (size_t)NTOK * QKVN * 2; // 25.2 MB
    const size_t B_SCR   = (size_t)NTOK * EDIM * 4; // 33.6 MB (h2 fp32; aliases Q/K/Vt)
    const size_t B_FF1   = (size_t)NTOK * FF * 2;   // 67.1 MB
    const size_t NEED = B_WQKV + B_WO + 3 * B_WFF + B_HATTN + B_QKV + B_SCR + B_FF1;
    if (ws_size < NEED) return;   // diagnostic: clean absmax-fail instead of GPU fault

    char* ws = (char*)d_ws;
    size_t off = 0;
    auto alloc = [&](size_t bytes) -> void* {
        void* p = ws + off;
        off += (bytes + 255) & ~(size_t)255;
        return p;
    };
    bf16* wqkv_b = (bf16*)alloc(B_WQKV);
    bf16* wo_b   = (bf16*)alloc(B_WO);
    bf16* w1_b   = (bf16*)alloc(B_WFF);
    bf16* w3_b   = (bf16*)alloc(B_WFF);
    bf16* w2_b   = (bf16*)alloc(B_WFF);
    bf16* h_attn = (bf16*)alloc(B_HATTN);           // h, then attn_out
    bf16* qkv_g  = (bf16*)alloc(B_QKV);             // qkv, then g
    char* scr    = (char*)alloc(B_SCR);             // Q/K/Vt region, then h2
    bf16* Qb  = (bf16*)scr;                                         // 16.8 MB
    bf16* Kb  = (bf16*)(scr + (size_t)BATCH * NH * SEQ * HD * 2);   //  4.2 MB
    bf16* Vtb = (bf16*)(scr + (size_t)BATCH * (NH + NKV) * SEQ * HD * 2); // 4.2 MB
    float* h2 = (float*)scr;                        // aliases Q/K/Vt (dead by then)
    bf16* ff1 = (bf16*)alloc(B_FF1);                // u, then act (in-place SwiGLU)
    bf16* g_b = qkv_g;                              // reuse (qkv dead after preps)

    // 1. weights -> bf16
    cvt_f32_bf16<<<512, 256, 0, stream>>>(wqkv, wqkv_b, (long)(SZ_WQKV / 4));
    cvt_f32_bf16<<<512, 256, 0, stream>>>(wo,   wo_b,   (long)(SZ_WO / 4));
    cvt_f32_bf16<<<512, 256, 0, stream>>>(w1,   w1_b,   (long)(SZ_WFF / 4));
    cvt_f32_bf16<<<512, 256, 0, stream>>>(w3,   w3_b,   (long)(SZ_WFF / 4));
    cvt_f32_bf16<<<512, 256, 0, stream>>>(w2,   w2_b,   (long)(SZ_WFF / 4));
    // 2. h = rmsnorm(x) * attn_norm_w  (bf16)
    rmsnorm_bf16<<<NTOK, 256, 0, stream>>>(x, anw, h_attn);
    // 3. qkv = h @ w_qkv^T  (bf16 out)
    gemm_nt<1><<<dim3(QKVN / 128, NTOK / 128), 256, 0, stream>>>(
        h_attn, wqkv_b, qkv_g, nullptr, NTOK, QKVN, EDIM);
    // 4. RoPE + layout prep (Q prescaled by 0.125)
    rope_prep<<<NTOK, 256, 0, stream>>>(qkv_g, fr, Qb, Kb);
    v_prep<<<BATCH * NKV * (SEQ / 64), 256, 0, stream>>>(qkv_g, Vtb);
    // 5. attention -> attn_out (bf16, [4096,2048]); grid (bh, qt) for balance
    attn_fwd<<<dim3(BATCH * NH, SEQ / 128), 256, 0, stream>>>(Qb, Kb, Vtb, h_attn);
    // 6. h2 = x + attn_out @ w_o^T  (fp32; h2 aliases dead Q/K/Vt)
    gemm_nt<2><<<dim3(EDIM / 128, NTOK / 128), 256, 0, stream>>>(
        h_attn, wo_b, h2, x, NTOK, EDIM, EDIM);
    // 7. g = rmsnorm(h2) * ff_norm_w (bf16)
    rmsnorm_bf16<<<NTOK, 256, 0, stream>>>(h2, fnw, g_b);
    // 8. u = g @ w1^T (bf16), then act = silu(u) * (g @ w3^T) in-place over ff1
    gemm_nt<1><<<dim3(FF / 128, NTOK / 128), 256, 0, stream>>>(
        g_b, w1_b, ff1, nullptr, NTOK, FF, EDIM);
    gemm_nt<3><<<dim3(FF / 128, NTOK / 128), 256, 0, stream>>>(
        g_b, w3_b, ff1, nullptr, NTOK, FF, EDIM);
    // 9. out = h2 + act @ w2^T  (fp32)
    gemm_nt<2><<<dim3(EDIM / 128, NTOK / 128), 256, 0, stream>>>(
        ff1, w2_b, out, h2, NTOK, EDIM, FF);
    (void)in_sizes; (void)n_in; (void)out_size; (void)ws_size;
}

// Round 6
// 1079.482 us; speedup vs baseline: 1.1341x; 1.0322x over previous
//
#include <hip/hip_runtime.h>
#include <hip/hip_bf16.h>
#include <cstdint>
#include <cstddef>

typedef __bf16 bf16;
typedef __bf16 bf16x2 __attribute__((ext_vector_type(2)));
typedef __bf16 bf16x4 __attribute__((ext_vector_type(4)));
typedef __bf16 bf16x8 __attribute__((ext_vector_type(8)));
typedef float f32x4 __attribute__((ext_vector_type(4)));
typedef float f32x16 __attribute__((ext_vector_type(16)));

// ---------------- constants ----------------
#define EDIM 2048
#define SEQ  2048
#define BATCH 2
#define NH   32
#define NKV  8
#define HD   64
#define FF   8192
#define NTOK 4096          // BATCH*SEQ
#define QKVN 3072          // EDIM + 2*512

// async 16B global -> LDS (lane-contiguous LDS layout required)
__device__ __forceinline__ void gld_lds16(const void* gp, void* lp) {
    __builtin_amdgcn_global_load_lds(
        (__attribute__((address_space(1))) void*)(gp),
        (__attribute__((address_space(3))) void*)(lp), 16, 0, 0);
}

// ---- shared block remap: XCD chunk + 8x8 supertile (bijective when nwg%64==0,
//      gx%8==0, gy%8==0; falls back to identity otherwise) ----
__device__ __forceinline__ void remap_xcd(int& bx, int& by) {
    int gx = gridDim.x, gy = gridDim.y;
    int nwg = gx * gy;
    if (((nwg & 63) | (gx & 7) | (gy & 7)) == 0) {
        int l = bx + gx * by;
        int nl = (l & 7) * (nwg >> 3) + (l >> 3);   // XCD gets contiguous range
        int s = nl >> 6, r = nl & 63;               // 8x8 supertile of blocks
        int spr = gx >> 3;                          // supertiles per row
        bx = (s % spr) * 8 + (r & 7);
        by = (s / spr) * 8 + (r >> 3);
    }
}

// ---------------- fp32 -> bf16 convert ----------------
__global__ __launch_bounds__(256)
void cvt_f32_bf16(const float* __restrict__ in, bf16* __restrict__ out, long n4) {
    long i = (long)blockIdx.x * blockDim.x + threadIdx.x;
    long stride = (long)gridDim.x * blockDim.x;
    for (; i < n4; i += stride) {
        float4 v = ((const float4*)in)[i];
        bf16x4 o;
        o[0] = (bf16)v.x; o[1] = (bf16)v.y; o[2] = (bf16)v.z; o[3] = (bf16)v.w;
        ((bf16x4*)out)[i] = o;
    }
}

// ---------------- RMSNorm: fp32 row -> bf16 row ----------------
__global__ __launch_bounds__(256)
void rmsnorm_bf16(const float* __restrict__ x, const float* __restrict__ w,
                  bf16* __restrict__ out) {
    __shared__ float red[4];
    const int row = blockIdx.x;
    const long base = (long)row * EDIM;
    const int t = threadIdx.x;
    float4 v0 = *(const float4*)(x + base + t * 4);
    float4 v1 = *(const float4*)(x + base + 1024 + t * 4);
    float ss = v0.x*v0.x + v0.y*v0.y + v0.z*v0.z + v0.w*v0.w
             + v1.x*v1.x + v1.y*v1.y + v1.z*v1.z + v1.w*v1.w;
    #pragma unroll
    for (int off = 1; off < 64; off <<= 1) ss += __shfl_xor(ss, off, 64);
    if ((t & 63) == 0) red[t >> 6] = ss;
    __syncthreads();
    float tot = red[0] + red[1] + red[2] + red[3];
    float inv = rsqrtf(tot * (1.0f / EDIM) + 1e-5f);
    float4 w0 = *(const float4*)(w + t * 4);
    float4 w1 = *(const float4*)(w + 1024 + t * 4);
    bf16x4 o0, o1;
    o0[0] = (bf16)(v0.x * inv * w0.x); o0[1] = (bf16)(v0.y * inv * w0.y);
    o0[2] = (bf16)(v0.z * inv * w0.z); o0[3] = (bf16)(v0.w * inv * w0.w);
    o1[0] = (bf16)(v1.x * inv * w1.x); o1[1] = (bf16)(v1.y * inv * w1.y);
    o1[2] = (bf16)(v1.z * inv * w1.z); o1[3] = (bf16)(v1.w * inv * w1.w);
    *(bf16x4*)(out + base + t * 4) = o0;
    *(bf16x4*)(out + base + 1024 + t * 4) = o1;
}

// ---------------- NT GEMM: C[M,N] = A[M,K] * B[N,K]^T ----------------
// m97 structure: 128x128 tile, BK=32, 4 waves, 4x4 of mfma_f32_16x16x32_bf16
// (256,4): 120 regs (56 VGPR + 64 AGPR) fits 4 blocks/CU -> more cross-block
// overlap of the per-K-step barrier drains.
// EPI: 0 = f32 store, 1 = bf16 store, 2 = f32 store + f32 residual add
template<int EPI>
__global__ __launch_bounds__(256, 4)
void gemm_nt(const bf16* __restrict__ A, const bf16* __restrict__ B,
             void* __restrict__ Cv, const float* __restrict__ res,
             int M, int N, int K) {
    __shared__ bf16 As[128 * 32];
    __shared__ bf16 Bs[128 * 32];
    const int tid = threadIdx.x;
    const int lane = tid & 63;
    const int wave = tid >> 6;
    const int wm = (wave >> 1) * 64;
    const int wn = (wave & 1) * 64;

    int bx = blockIdx.x, by = blockIdx.y;
    remap_xcd(bx, by);
    const int bm = by * 128;
    const int bn = bx * 128;
    const int lrow = lane & 15;
    const int koff = (lane >> 4) * 8;

    f32x4 acc[4][4] = {};

    for (int k0 = 0; k0 < K; k0 += 32) {
        __syncthreads();
        #pragma unroll
        for (int t = 0; t < 2; ++t) {
            int c = tid + t * 256;           // 512 chunks of 16B per tile
            int r = c >> 2;
            int kc = (c & 3) * 8;
            gld_lds16(A + (long)(bm + r) * K + k0 + kc, As + c * 8);
            gld_lds16(B + (long)(bn + r) * K + k0 + kc, Bs + c * 8);
        }
        __syncthreads();
        bf16x8 af[4], bfr[4];
        #pragma unroll
        for (int t = 0; t < 4; ++t) {
            af[t]  = *(const bf16x8*)(As + (wm + t * 16 + lrow) * 32 + koff);
            bfr[t] = *(const bf16x8*)(Bs + (wn + t * 16 + lrow) * 32 + koff);
        }
        #pragma unroll
        for (int i = 0; i < 4; ++i)
            #pragma unroll
            for (int j = 0; j < 4; ++j)
                acc[i][j] = __builtin_amdgcn_mfma_f32_16x16x32_bf16(af[i], bfr[j], acc[i][j], 0, 0, 0);
    }

    const int row0 = bm + wm + (lane >> 4) * 4;
    const int col0 = bn + wn + (lane & 15);
    #pragma unroll
    for (int i = 0; i < 4; ++i) {
        #pragma unroll
        for (int j = 0; j < 4; ++j) {
            int col = col0 + j * 16;
            #pragma unroll
            for (int r = 0; r < 4; ++r) {
                long idx = (long)(row0 + i * 16 + r) * N + col;
                float v = acc[i][j][r];
                if (EPI == 0) {
                    ((float*)Cv)[idx] = v;
                } else if (EPI == 1) {
                    ((bf16*)Cv)[idx] = (bf16)v;
                } else {
                    ((float*)Cv)[idx] = v + res[idx];
                }
            }
        }
    }
}

// ---------------- fused SwiGLU GEMM: C = silu(A*B1^T) * (A*B3^T), bf16 out ----------------
// Same 128x128 m97 structure but BOTH matmuls in one K-loop: A staged once,
// B1+B3 staged alongside, 32 MFMA per K-step against the same 2 barriers
// (doubles MFMA-per-barrier-drain: the measured bottleneck), and the SwiGLU
// combine happens in-register (no u round-trip through HBM, no EPI3 RMW pass).
__global__ __launch_bounds__(256, 2)
void gemm_ff(const bf16* __restrict__ A, const bf16* __restrict__ B1,
             const bf16* __restrict__ B3, bf16* __restrict__ C,
             int M, int N, int K) {
    __shared__ bf16 As[128 * 32];
    __shared__ bf16 B1s[128 * 32];
    __shared__ bf16 B3s[128 * 32];
    const int tid = threadIdx.x;
    const int lane = tid & 63;
    const int wave = tid >> 6;
    const int wm = (wave >> 1) * 64;
    const int wn = (wave & 1) * 64;

    int bx = blockIdx.x, by = blockIdx.y;
    remap_xcd(bx, by);
    const int bm = by * 128;
    const int bn = bx * 128;
    const int lrow = lane & 15;
    const int koff = (lane >> 4) * 8;

    f32x4 accu[4][4] = {};
    f32x4 accv[4][4] = {};

    for (int k0 = 0; k0 < K; k0 += 32) {
        __syncthreads();
        #pragma unroll
        for (int t = 0; t < 2; ++t) {
            int c = tid + t * 256;           // 512 chunks of 16B per tile
            int r = c >> 2;
            int kc = (c & 3) * 8;
            gld_lds16(A  + (long)(bm + r) * K + k0 + kc, As  + c * 8);
            gld_lds16(B1 + (long)(bn + r) * K + k0 + kc, B1s + c * 8);
            gld_lds16(B3 + (long)(bn + r) * K + k0 + kc, B3s + c * 8);
        }
        __syncthreads();
        bf16x8 af[4], b1f[4], b3f[4];
        #pragma unroll
        for (int t = 0; t < 4; ++t) {
            af[t]  = *(const bf16x8*)(As  + (wm + t * 16 + lrow) * 32 + koff);
            b1f[t] = *(const bf16x8*)(B1s + (wn + t * 16 + lrow) * 32 + koff);
            b3f[t] = *(const bf16x8*)(B3s + (wn + t * 16 + lrow) * 32 + koff);
        }
        #pragma unroll
        for (int i = 0; i < 4; ++i)
            #pragma unroll
            for (int j = 0; j < 4; ++j) {
                accu[i][j] = __builtin_amdgcn_mfma_f32_16x16x32_bf16(af[i], b1f[j], accu[i][j], 0, 0, 0);
                accv[i][j] = __builtin_amdgcn_mfma_f32_16x16x32_bf16(af[i], b3f[j], accv[i][j], 0, 0, 0);
            }
    }

    const int row0 = bm + wm + (lane >> 4) * 4;
    const int col0 = bn + wn + (lane & 15);
    #pragma unroll
    for (int i = 0; i < 4; ++i) {
        #pragma unroll
        for (int j = 0; j < 4; ++j) {
            int col = col0 + j * 16;
            #pragma unroll
            for (int r = 0; r < 4; ++r) {
                long idx = (long)(row0 + i * 16 + r) * N + col;
                float u = accu[i][j][r];
                float v = accv[i][j][r];
                float sl = u / (1.0f + __expf(-u));
                C[idx] = (bf16)(sl * v);
            }
        }
    }
}

// ---------------- RoPE prep: qkv bf16 [4096,3072] -> Q [B,H,S,64], K [B,KH,S,64] ----------------
// NOTE: Q is prescaled by 1/sqrt(HD) = 0.125 here (exact power-of-2 in bf16),
// so attn_fwd uses raw QK^T scores.
__global__ __launch_bounds__(256)
void rope_prep(const bf16* __restrict__ qkv, const float* __restrict__ fr,
               bf16* __restrict__ Qo, bf16* __restrict__ Ko) {
    const int row = blockIdx.x;            // b*SEQ + s
    const int b = row >> 11, s = row & 2047;
    const int t = threadIdx.x;
    const long rbase = (long)row * QKVN;
    #pragma unroll
    for (int i = 0; i < 4; ++i) {          // 1024 q pairs
        int p = t + i * 256;
        int hh = p >> 5, d = p & 31;
        bf16x2 xv = *(const bf16x2*)(qkv + rbase + hh * 64 + 2 * d);
        float x0 = (float)xv[0], x1 = (float)xv[1];
        float2 cs = *(const float2*)(fr + (long)(s * 32 + d) * 2);
        bf16x2 o;
        o[0] = (bf16)((x0 * cs.x - x1 * cs.y) * 0.125f);
        o[1] = (bf16)((x1 * cs.x + x0 * cs.y) * 0.125f);
        *(bf16x2*)(Qo + ((long)(b * NH + hh) * SEQ + s) * HD + 2 * d) = o;
    }
    {                                       // 256 k pairs
        int kh = t >> 5, d = t & 31;
        bf16x2 xv = *(const bf16x2*)(qkv + rbase + EDIM + kh * 64 + 2 * d);
        float x0 = (float)xv[0], x1 = (float)xv[1];
        float2 cs = *(const float2*)(fr + (long)(s * 32 + d) * 2);
        bf16x2 o;
        o[0] = (bf16)(x0 * cs.x - x1 * cs.y);
        o[1] = (bf16)(x1 * cs.x + x0 * cs.y);
        *(bf16x2*)(Ko + ((long)(b * NKV + kh) * SEQ + s) * HD + 2 * d) = o;
    }
}

// ---------------- V prep: transpose into [B,KH,S/64,hd=64,kk=64] bf16 tiles ----------------
__global__ __launch_bounds__(256)
void v_prep(const bf16* __restrict__ qkv, bf16* __restrict__ Vt) {
    __shared__ bf16 tile[64 * 72];          // +8 pad to break transpose conflicts
    const int blk = blockIdx.x;             // b*256 + kvh*32 + st
    const int b = blk >> 8;
    const int kvh = (blk >> 5) & 7;
    const int st = blk & 31;
    const int t = threadIdx.x;
    #pragma unroll
    for (int i = 0; i < 2; ++i) {
        int c = t + i * 256;                // 512 chunks
        int kk = c >> 3, hdo = (c & 7) * 8;
        bf16x8 v = *(const bf16x8*)(qkv + (long)(b * SEQ + st * 64 + kk) * QKVN + 2560 + kvh * 64 + hdo);
        *(bf16x8*)(tile + kk * 72 + hdo) = v;
    }
    __syncthreads();
    const long obase = ((long)(b * NKV + kvh) * 32 + st) * 4096;
    #pragma unroll
    for (int i = 0; i < 2; ++i) {
        int c = t + i * 256;
        int hd = c >> 3, ko = (c & 7) * 8;
        bf16x8 v;
        #pragma unroll
        for (int j = 0; j < 8; ++j) v[j] = tile[(ko + j) * 72 + hd];
        *(bf16x8*)(Vt + obase + hd * 64 + ko) = v;
    }
}

// ---------------- flash attention (causal, GQA 4:1), swapped-QK^T ----------------
// 4 waves/block, each wave owns 32 q-rows independently (no block barriers).
// Grid = (bh, qt) so each CU draws mixed-qt blocks -> uniform per-CU work.
// Per iteration: 64 keys; ALL K+V fragment loads issued at the top (latency
// hidden under the two 32-key compute halves). Softmax per half: 15 in-reg
// fmax + ONE __shfl_xor(.,32); defer-max (T13) shared across halves.
// P -> PV via per-wave LDS with row-XOR swizzle sw=(ql^(ql>>3))&3.
// Q is prescaled by 0.125 in rope_prep.
__global__ __launch_bounds__(256, 3)
void attn_fwd(const bf16* __restrict__ Q, const bf16* __restrict__ K,
              const bf16* __restrict__ Vt, bf16* __restrict__ Out) {
    __shared__ bf16 Ps[4][32][40];           // per-wave P, 40-elem stride (80B = 5x16B)
    const int tid = threadIdx.x, lane = tid & 63, w = tid >> 6;
    const int bh = blockIdx.x;               // batch*head (fast grid dim for balance)
    const int qt = blockIdx.y;               // 128-row q tile
    const int b = bh >> 5, h = bh & 31;
    const int kvh = h >> 2;
    const int ql = lane & 31;                // q-row owned by this lane
    const int hh = lane >> 5;                // lane half
    const int sw = (ql ^ (ql >> 3)) & 3;     // LDS 16B-block swizzle key
    const int q0 = qt * 128 + w * 32;        // wave's q base within seq
    const int qmax = q0 + 31;
    const long qbase  = ((long)(b * NH + h) * SEQ + q0) * HD;
    const long kvbase = ((long)(b * NKV + kvh) * SEQ) * HD;
    bf16* Pw = &Ps[w][0][0];

    // Q fragments: qa[ds] = Q[q0+ql][ds*16 + hh*8 .. +8]  (B-operand layout)
    bf16x8 qa[4];
    #pragma unroll
    for (int ds = 0; ds < 4; ++ds)
        qa[ds] = *(const bf16x8*)(Q + qbase + (long)ql * HD + ds * 16 + hh * 8);

    f32x16 oacc[2] = {};                     // O^T accumulators (2 d-tiles of 32)
    float mi = -1e30f, li = 0.f;

    // 64-key tiles; last-tile second half may be skipped (fully masked)
    const int nt64 = qt * 2 + 1 + (w >> 1);
    for (int kt = 0; kt < nt64; ++kt) {
        const bf16* Kt  = K  + kvbase + (long)kt * (64 * HD);
        const bf16* Vtt = Vt + kvbase + (long)kt * 4096;
        // ---- batch-issue ALL loads for this 64-key tile ----
        bf16x8 ka[2][4], va[2][2][2];
        #pragma unroll
        for (int h2 = 0; h2 < 2; ++h2)
            #pragma unroll
            for (int ds = 0; ds < 4; ++ds)
                ka[h2][ds] = *(const bf16x8*)(Kt + (h2 * 32 + ql) * HD + ds * 16 + hh * 8);
        #pragma unroll
        for (int h2 = 0; h2 < 2; ++h2)
            #pragma unroll
            for (int t = 0; t < 2; ++t)
                #pragma unroll
                for (int c = 0; c < 2; ++c)
                    va[h2][t][c] = *(const bf16x8*)(Vtt + (t * 32 + ql) * 64 + h2 * 32 + c * 16 + hh * 8);
        const bool lastt = (kt == nt64 - 1);
        #pragma unroll
        for (int h2 = 0; h2 < 2; ++h2) {
            if (h2 == 1 && kt * 64 + 32 > qmax) break;   // wave-uniform skip
            // S^T[k][q] over 32 keys (4 mfma over d-slices of 16)
            f32x16 s = {};
            #pragma unroll
            for (int ds = 0; ds < 4; ++ds)
                s = __builtin_amdgcn_mfma_f32_32x32x16_bf16(ka[h2][ds], qa[ds], s, 0, 0, 0);
            if (lastt) {
                #pragma unroll
                for (int r = 0; r < 16; ++r) {
                    int kk = kt * 64 + h2 * 32 + (r & 3) + 8 * (r >> 2) + 4 * hh;
                    if (kk > q0 + ql) s[r] = -1e30f;
                }
            }
            // row max: 15 in-register + one cross-half shuffle
            float tmax = s[0];
            #pragma unroll
            for (int r = 1; r < 16; ++r) tmax = fmaxf(tmax, s[r]);
            tmax = fmaxf(tmax, __shfl_xor(tmax, 32, 64));
            // defer-max: rescale only when the running max grows
            if (!__all(tmax <= mi)) {
                float mnew = fmaxf(mi, tmax);
                float alpha = __expf(mi - mnew);
                li *= alpha;
                #pragma unroll
                for (int r = 0; r < 16; ++r) { oacc[0][r] *= alpha; oacc[1][r] *= alpha; }
                mi = mnew;
            }
            // p = exp(s - mi); P[ql][k] as 4x b64, swizzled 16B blocks
            float psum = 0.f;
            #pragma unroll
            for (int g2 = 0; g2 < 4; ++g2) {
                bf16x4 pw;
                #pragma unroll
                for (int j = 0; j < 4; ++j) {
                    float p = __expf(s[g2 * 4 + j] - mi);
                    psum += p;
                    pw[j] = (bf16)p;
                }
                *(bf16x4*)(Pw + ql * 40 + ((g2 ^ sw) << 3) + 4 * hh) = pw;
            }
            psum += __shfl_xor(psum, 32, 64);
            li += psum;
            // B-fragments from swizzled LDS
            bf16x8 p0 = *(const bf16x8*)(Pw + ql * 40 + ((hh ^ sw) << 3));
            bf16x8 p1 = *(const bf16x8*)(Pw + ql * 40 + (((2 + hh) ^ sw) << 3));
            // PV: O^T[d][q] += V^T[d][k] * P^T[k][q]
            #pragma unroll
            for (int t = 0; t < 2; ++t) {
                oacc[t] = __builtin_amdgcn_mfma_f32_32x32x16_bf16(va[h2][t][0], p0, oacc[t], 0, 0, 0);
                oacc[t] = __builtin_amdgcn_mfma_f32_32x32x16_bf16(va[h2][t][1], p1, oacc[t], 0, 0, 0);
            }
        }
    }

    // epilogue: lane owns row q = q0+ql; d = t*32 + rg*8 + 4*hh + (0..3)
    float inv = 1.0f / li;
    const long obase = ((long)b * SEQ + q0 + ql) * EDIM + h * 64;
    #pragma unroll
    for (int t = 0; t < 2; ++t)
        #pragma unroll
        for (int rg = 0; rg < 4; ++rg) {
            bf16x4 o4;
            #pragma unroll
            for (int j = 0; j < 4; ++j) o4[j] = (bf16)(oacc[t][rg * 4 + j] * inv);
            *(bf16x4*)(Out + obase + t * 32 + rg * 8 + hh * 4) = o4;
        }
}

// ---------------- launcher ----------------
extern "C" void kernel_launch(void* const* d_in, const int* in_sizes, int n_in,
                              void* d_out, int out_size, void* d_ws, size_t ws_size,
                              hipStream_t stream) {
    const float* x    = (const float*)d_in[0];
    // d_in[1] = attention_mask (always causal tril; handled analytically)
    const float* fr   = (const float*)d_in[2];
    const float* wqkv = (const float*)d_in[3];
    const float* wo   = (const float*)d_in[4];
    const float* w1   = (const float*)d_in[5];
    const float* w2   = (const float*)d_in[6];
    const float* w3   = (const float*)d_in[7];
    const float* anw  = (const float*)d_in[8];
    const float* fnw  = (const float*)d_in[9];
    float* out = (float*)d_out;

    // ---- workspace budget (aliased layout), ~252 MiB ----
    const size_t SZ_WQKV = (size_t)QKVN * EDIM;     // 6291456
    const size_t SZ_WO   = (size_t)EDIM * EDIM;     // 4194304
    const size_t SZ_WFF  = (size_t)FF * EDIM;       // 16777216
    const size_t B_WQKV  = SZ_WQKV * 2;             // 12.6 MB
    const size_t B_WO    = SZ_WO * 2;               //  8.4 MB
    const size_t B_WFF   = SZ_WFF * 2;              // 33.6 MB
    const size_t B_HATTN = (size_t)NTOK * EDIM * 2; // 16.8 MB
    const size_t B_QKV   = (size_t)NTOK * QKVN * 2; // 25.2 MB
    const size_t B_SCR   = (size_t)NTOK * EDIM * 4; // 33.6 MB (h2 fp32; aliases Q/K/Vt)
    const size_t B_FF1   = (size_t)NTOK * FF * 2;   // 67.1 MB
    const size_t NEED = B_WQKV + B_WO + 3 * B_WFF + B_HATTN + B_QKV + B_SCR + B_FF1;
    if (ws_size < NEED) return;   // diagnostic: clean absmax-fail instead of GPU fault

    char* ws = (char*)d_ws;
    size_t off = 0;
    auto alloc = [&](size_t bytes) -> void* {
        void* p = ws + off;
        off += (bytes + 255) & ~(size_t)255;
        return p;
    };
    bf16* wqkv_b = (bf16*)alloc(B_WQKV);
    bf16* wo_b   = (bf16*)alloc(B_WO);
    bf16* w1_b   = (bf16*)alloc(B_WFF);
    bf16* w3_b   = (bf16*)alloc(B_WFF);
    bf16* w2_b   = (bf16*)alloc(B_WFF);
    bf16* h_attn = (bf16*)alloc(B_HATTN);           // h, then attn_out
    bf16* qkv_g  = (bf16*)alloc(B_QKV);             // qkv, then g
    char* scr    = (char*)alloc(B_SCR);             // Q/K/Vt region, then h2
    bf16* Qb  = (bf16*)scr;                                         // 16.8 MB
    bf16* Kb  = (bf16*)(scr + (size_t)BATCH * NH * SEQ * HD * 2);   //  4.2 MB
    bf16* Vtb = (bf16*)(scr + (size_t)BATCH * (NH + NKV) * SEQ * HD * 2); // 4.2 MB
    float* h2 = (float*)scr;                        // aliases Q/K/Vt (dead by then)
    bf16* ff1 = (bf16*)alloc(B_FF1);                // SwiGLU activation (single write)
    bf16* g_b = qkv_g;                              // reuse (qkv dead after preps)

    // 1. weights -> bf16
    cvt_f32_bf16<<<512, 256, 0, stream>>>(wqkv, wqkv_b, (long)(SZ_WQKV / 4));
    cvt_f32_bf16<<<512, 256, 0, stream>>>(wo,   wo_b,   (long)(SZ_WO / 4));
    cvt_f32_bf16<<<512, 256, 0, stream>>>(w1,   w1_b,   (long)(SZ_WFF / 4));
    cvt_f32_bf16<<<512, 256, 0, stream>>>(w3,   w3_b,   (long)(SZ_WFF / 4));
    cvt_f32_bf16<<<512, 256, 0, stream>>>(w2,   w2_b,   (long)(SZ_WFF / 4));
    // 2. h = rmsnorm(x) * attn_norm_w  (bf16)
    rmsnorm_bf16<<<NTOK, 256, 0, stream>>>(x, anw, h_attn);
    // 3. qkv = h @ w_qkv^T  (bf16 out)
    gemm_nt<1><<<dim3(QKVN / 128, NTOK / 128), 256, 0, stream>>>(
        h_attn, wqkv_b, qkv_g, nullptr, NTOK, QKVN, EDIM);
    // 4. RoPE + layout prep (Q prescaled by 0.125)
    rope_prep<<<NTOK, 256, 0, stream>>>(qkv_g, fr, Qb, Kb);
    v_prep<<<BATCH * NKV * (SEQ / 64), 256, 0, stream>>>(qkv_g, Vtb);
    // 5. attention -> attn_out (bf16, [4096,2048]); grid (bh, qt) for balance
    attn_fwd<<<dim3(BATCH * NH, SEQ / 128), 256, 0, stream>>>(Qb, Kb, Vtb, h_attn);
    // 6. h2 = x + attn_out @ w_o^T  (fp32; h2 aliases dead Q/K/Vt)
    gemm_nt<2><<<dim3(EDIM / 128, NTOK / 128), 256, 0, stream>>>(
        h_attn, wo_b, h2, x, NTOK, EDIM, EDIM);
    // 7. g = rmsnorm(h2) * ff_norm_w (bf16)
    rmsnorm_bf16<<<NTOK, 256, 0, stream>>>(h2, fnw, g_b);
    // 8. act = silu(g @ w1^T) * (g @ w3^T)  -- ONE fused kernel, in-register SwiGLU
    gemm_ff<<<dim3(FF / 128, NTOK / 128), 256, 0, stream>>>(
        g_b, w1_b, w3_b, ff1, NTOK, FF, EDIM);
    // 9. out = h2 + act @ w2^T  (fp32)
    gemm_nt<2><<<dim3(EDIM / 128, NTOK / 128), 256, 0, stream>>>(
        ff1, w2_b, out, h2, NTOK, EDIM, FF);
    (void)in_sizes; (void)n_in; (void)out_size; (void)ws_size;
}